// Round 5
// baseline (1200.693 us; speedup 1.0000x reference)
//
#include <hip/hip_runtime.h>
#include <hip/hip_bf16.h>
#include <math.h>

// CrossAttentionFusion on MI355X.
// softmax over one key == 1  =>  mha1(q_in, kv) = kv@Wc.T + bc,
//   Wc = Wo@Wv (fused once), bc = Wo@bv + bo.
// R10: graph-level optimization; hot 256^2 8-phase loop FROZEN (R7-R9 showed
// it at ~845 TF/active-CU = published plain-HIP full-stack level, m248).
// (a) 768^3 weight-combines moved off the 256^2 kernel (9-block grid, ~30us
//     each) onto a 128^2 2-phase kernel (36 blocks, ~7us) ported from the
//     R5-verified code.
// (b) LN algebraically fused into the FFN GEMMs:
//     h = gelu(LN(x)@W1.T+b1) = gelu(inv(r)*(x@W1g.T - m(r)*sg) + bb),
//       W1g[n,k]=W1[n,k]*g[k] (folded in conv8), sg=rowsum(W1g),
//       bb=W1@b+b1 (sgbb_k), (m,inv) per row from lnstats_k.
//     FFN2 residual = LN(pbuf) computed in its epilogue:
//       (pbuf-m)*inv*g + b. Kills 2 ln_k dispatches + the vbuf round-trip.
//     pbuf is now a standalone buffer (must outlive FFN1 as residual src).

typedef unsigned short u16;
typedef __bf16 bf16_t;
typedef bf16_t bf16x8 __attribute__((ext_vector_type(8)));
typedef float f32x4 __attribute__((ext_vector_type(4)));

#define BROWS 16384   // batch
#define EDIM  768

__device__ __forceinline__ u16 f2bf(float f) {
    union { float f; unsigned u; } v; v.f = f;
    return (u16)((v.u + 0x7FFFu + ((v.u >> 16) & 1u)) >> 16);  // RNE
}
__device__ __forceinline__ float bf2f(u16 h) {
    union { unsigned u; float f; } v; v.u = ((unsigned)h) << 16;
    return v.f;
}
// gelu via x*sigmoid(1.5957691*x + 0.0713548*x^3); exp2/rcp HW instrs.
__device__ __forceinline__ float gelu_f(float x) {
    float t = x * x;
    float p = fmaf(0.102943268f, t, 2.30221895f);   // log2(e) folded in
    float e = __builtin_amdgcn_exp2f(-x * p);
    return x * __builtin_amdgcn_rcpf(1.0f + e);
}

// async global->LDS, 16B/lane. LDS dest is wave-uniform base + lane*16.
__device__ __forceinline__ void gld16(const u16* g, u16* l) {
    __builtin_amdgcn_global_load_lds(
        (__attribute__((address_space(1))) void*)g,
        (__attribute__((address_space(3))) void*)l, 16, 0, 0);
}

// ---- batched f32->bf16 conversion: 8 tensors, one dispatch ----
// Tensors 0 (fi_W1) and 2 (ft_W1) are column-scaled by their LN gain g
// (the LN-fusion fold: W1g[n,k] = W1[n,k]*g[k]).
struct ConvBatch {
    const float *s0, *s1, *s2, *s3, *s4, *s5, *s6, *s7;
    u16 *d0, *d1, *d2, *d3, *d4, *d5, *d6, *d7;
    const float *g0, *g2;    // column scales for tensors 0 and 2 (len 768)
};
#define CB0 2304   // fi_W1 3072*768
#define CB1 2304   // fi_W2
#define CB2 2304   // ft_W1
#define CB3 2304   // ft_W2
#define CB4 1152   // fp_W 768*1536
#define CB5 576    // it_Wo 768*768
#define CB6 576    // ti_Wo
#define CB7 12288  // text 16384*768
#define CONV_BLOCKS (CB0+CB1+CB2+CB3+CB4+CB5+CB6+CB7)

__global__ void __launch_bounds__(256) conv8_k(ConvBatch cb) {
    int b = blockIdx.x;
    const float* s; u16* d; const float* gs = nullptr;
    if      (b < CB0)          { s = cb.s0; d = cb.d0; gs = cb.g0; }
    else if ((b -= CB0) < CB1) { s = cb.s1; d = cb.d1; }
    else if ((b -= CB1) < CB2) { s = cb.s2; d = cb.d2; gs = cb.g2; }
    else if ((b -= CB2) < CB3) { s = cb.s3; d = cb.d3; }
    else if ((b -= CB3) < CB4) { s = cb.s4; d = cb.d4; }
    else if ((b -= CB4) < CB5) { s = cb.s5; d = cb.d5; }
    else if ((b -= CB5) < CB6) { s = cb.s6; d = cb.d6; }
    else    { b -= CB6;          s = cb.s7; d = cb.d7; }
    int i = b * 256 + threadIdx.x;
    float4 v = ((const float4*)s)[i];
    if (gs) {   // row length 768 f32 = 192 float4s
        float4 gv = ((const float4*)gs)[i % 192];
        v.x *= gv.x; v.y *= gv.y; v.z *= gv.z; v.w *= gv.w;
    }
    ushort4 o;
    o.x = f2bf(v.x); o.y = f2bf(v.y); o.z = f2bf(v.z); o.w = f2bf(v.w);
    ((ushort4*)d)[i] = o;
}

// D[c,r] = bf16(S[r,c]) — transpose-convert (Wv.T for the weight combine).
__global__ void __launch_bounds__(256) f32_to_bf16_T_k(const float* __restrict__ S,
                                                       u16* __restrict__ D,
                                                       int R, int C) {
    __shared__ float t[32][33];
    const int r0 = blockIdx.y * 32, c0 = blockIdx.x * 32;
    const int tx = threadIdx.x & 31, ty = threadIdx.x >> 5;  // ty 0..7
#pragma unroll
    for (int i = ty; i < 32; i += 8) t[i][tx] = S[(long)(r0 + i) * C + c0 + tx];
    __syncthreads();
#pragma unroll
    for (int i = ty; i < 32; i += 8) D[(long)(c0 + i) * R + r0 + tx] = f2bf(t[tx][i]);
}

// bc[n] = bo[n] + dot(Wo[n,:], bv)
__global__ void __launch_bounds__(256) bias_comb_k(const float* __restrict__ Wo,
                                                   const float* __restrict__ bv,
                                                   const float* __restrict__ bo,
                                                   float* __restrict__ bc, int K) {
    const int n = blockIdx.x * 4 + (threadIdx.x >> 6);
    const int lane = threadIdx.x & 63;
    float s = 0.f;
    for (int k = lane; k < K; k += 64) s += Wo[(long)n * K + k] * bv[k];
#pragma unroll
    for (int o = 32; o > 0; o >>= 1) s += __shfl_down(s, o, 64);
    if (lane == 0) bc[n] = s + bo[n];
}

// sg[n] = dot(W1[n,:], g);  bb[n] = dot(W1[n,:], b) + b1[n]   (LN fusion)
__global__ void __launch_bounds__(256) sgbb_k(const float* __restrict__ W1,
                                              const float* __restrict__ g,
                                              const float* __restrict__ b,
                                              const float* __restrict__ b1,
                                              float* __restrict__ sg,
                                              float* __restrict__ bb, int K) {
    const int n = blockIdx.x * 4 + (threadIdx.x >> 6);
    const int lane = threadIdx.x & 63;
    float s = 0.f, t = 0.f;
    for (int k = lane; k < K; k += 64) {
        float w = W1[(long)n * K + k];
        s += w * g[k]; t += w * b[k];
    }
#pragma unroll
    for (int o = 32; o > 0; o >>= 1) {
        s += __shfl_down(s, o, 64); t += __shfl_down(t, o, 64);
    }
    if (lane == 0) { sg[n] = s; bb[n] = t + b1[n]; }
}

// per-row mean & rsqrt(var+eps) over 768 bf16 cols; one wave per row.
__global__ void __launch_bounds__(256) lnstats_k(const u16* __restrict__ X,
                                                 float* __restrict__ mrow,
                                                 float* __restrict__ irow) {
    const int row = blockIdx.x * 4 + (threadIdx.x >> 6);
    const int lane = threadIdx.x & 63;
    const u16* xr = X + (long)row * EDIM;
    float s = 0.f, s2 = 0.f;
#pragma unroll
    for (int j = 0; j < 3; j++) {
        ushort4 u = ((const ushort4*)xr)[lane + j * 64];
        float a0 = bf2f(u.x), a1 = bf2f(u.y), a2 = bf2f(u.z), a3 = bf2f(u.w);
        s  += a0 + a1 + a2 + a3;
        s2 += a0 * a0 + a1 * a1 + a2 * a2 + a3 * a3;
    }
#pragma unroll
    for (int o = 32; o > 0; o >>= 1) {
        s += __shfl_down(s, o, 64); s2 += __shfl_down(s2, o, 64);
    }
    if (lane == 0) {
        float mean = s * (1.0f / 768.0f);
        float var  = s2 * (1.0f / 768.0f) - mean * mean;
        mrow[row] = mean;
        irow[row] = rsqrtf(var + 1e-5f);
    }
}

// ---- small GEMM (128x128 tile, BK=32, 2-phase, 4 waves) for the 768^3
// weight combines. Ported from the R5-verified kernel, bf16-out only.
__global__ void __launch_bounds__(256) gemm128_k(
    const u16* __restrict__ A, int lda,
    const u16* __restrict__ W,
    u16* __restrict__ Cb, int ldcb, int K)
{
    __shared__ alignas(16) u16 sA[2][128 * 32];
    __shared__ alignas(16) u16 sB[2][128 * 32];
    const int tid  = threadIdx.x;
    const int lane = tid & 63;
    const int wave = tid >> 6;
    const int wm = wave >> 1, wn = wave & 1;
    const long m0 = (long)blockIdx.y * 128;
    const long n0 = (long)blockIdx.x * 128;
    const int r   = lane >> 2;
    const int cbk = lane & 3;
    const int cbs = cbk ^ ((r >> 1) & 3);
    const int c0 = wave * 2, c1 = wave * 2 + 1;
    const u16* gA0 = A + (m0 + c0 * 16 + r) * (long)lda + cbs * 8;
    const u16* gA1 = A + (m0 + c1 * 16 + r) * (long)lda + cbs * 8;
    const u16* gB0 = W + (n0 + c0 * 16 + r) * (long)K + cbs * 8;
    const u16* gB1 = W + (n0 + c1 * 16 + r) * (long)K + cbs * 8;
    auto stage = [&](int buf, int kk) {
        gld16(gA0 + kk, sA[buf] + c0 * 512);
        gld16(gA1 + kk, sA[buf] + c1 * 512);
        gld16(gB0 + kk, sB[buf] + c0 * 512);
        gld16(gB1 + kk, sB[buf] + c1 * 512);
    };
    const int quad = lane >> 4;
    const int l16  = lane & 15;
    int offA[4], offB[4];
#pragma unroll
    for (int t = 0; t < 4; t++) {
        const int rowA = wm * 64 + t * 16 + l16;
        const int rowB = wn * 64 + t * 16 + l16;
        offA[t] = rowA * 32 + (quad ^ ((rowA >> 1) & 3)) * 8;
        offB[t] = rowB * 32 + (quad ^ ((rowB >> 1) & 3)) * 8;
    }
    f32x4 acc[4][4];
#pragma unroll
    for (int i = 0; i < 4; i++)
#pragma unroll
        for (int j = 0; j < 4; j++) {
            f32x4 z = {0.f, 0.f, 0.f, 0.f};
            acc[i][j] = z;
        }
    stage(0, 0);
    __syncthreads();
    int buf = 0;
    for (int k0 = 0; k0 < K; k0 += 32) {
        const int nk = k0 + 32;
        if (nk < K) stage(buf ^ 1, nk);
        bf16x8 af[4], bfr[4];
#pragma unroll
        for (int t = 0; t < 4; t++) af[t]  = *(const bf16x8*)(sA[buf] + offA[t]);
#pragma unroll
        for (int t = 0; t < 4; t++) bfr[t] = *(const bf16x8*)(sB[buf] + offB[t]);
#pragma unroll
        for (int mt = 0; mt < 4; mt++)
#pragma unroll
            for (int nt = 0; nt < 4; nt++)
                acc[mt][nt] = __builtin_amdgcn_mfma_f32_16x16x32_bf16(
                    af[mt], bfr[nt], acc[mt][nt], 0, 0, 0);
        __syncthreads();
        buf ^= 1;
    }
#pragma unroll
    for (int mt = 0; mt < 4; mt++)
#pragma unroll
        for (int nt = 0; nt < 4; nt++) {
            const long col = n0 + wn * 64 + nt * 16 + l16;
#pragma unroll
            for (int rr = 0; rr < 4; rr++) {
                const long row = m0 + wm * 64 + mt * 16 + quad * 4 + rr;
                Cb[row * (long)ldcb + col] = f2bf(acc[mt][nt][rr]);
            }
        }
}

// C[m,n] = sum_k A[m,k] * W[n,k]  + epilogue.
// mode 0: v = acc (+bias) (+R f32) (+Rb bf16), opt gelu.
// mode 1: v = rowI[r]*(acc - rowM[r]*cg[col]) + bias[col]   (LN-fused FFN1)
// mode 2: v = acc + bias[col] + (Rb - rowM[r])*rowI[r]*cg[col] + cb2[col]
// 256x256 tile, 8 waves (2M x 4N), per-wave C = 128x64. One barrier/phase,
// fragment reads pipelined one phase ahead (counted lgkmcnt). (R9 loop.)
__global__ void __launch_bounds__(512, 2) gemm_bt(
    const u16* __restrict__ A, int lda,
    const u16* __restrict__ W,
    const float* __restrict__ bias,
    const float* __restrict__ R, int ldr,      // f32 residual (or null)
    const u16* __restrict__ Rb, int ldrb,      // bf16 residual (or null)
    const float* __restrict__ rowM,
    const float* __restrict__ rowI,
    const float* __restrict__ cg,
    const float* __restrict__ cb2,
    float* __restrict__ Cf, int ldcf,
    u16* __restrict__ Cb, int ldcb,
    int K, int do_gelu, int mode)
{
    __shared__ alignas(16) u16 sA[4][256 * 32];   // 4 k-half slots x 16KB
    __shared__ alignas(16) u16 sB[4][256 * 32];

    const int tid  = threadIdx.x;
    const int lane = tid & 63;
    const int wave = tid >> 6;     // 0..7
    const int wm = wave >> 2;      // 0..1  (M half)
    const int wn = wave & 3;       // 0..3  (N quarter)

    // XCD-aware swizzle: id%8 = XCD (round-robin dispatch). Give each XCD a
    // contiguous slab of row-tiles; sweep col-tiles fastest within the slab.
    int bm, bn;
    {
        const int gx = gridDim.x, gy = gridDim.y;
        const int id = blockIdx.y * gx + blockIdx.x;
        if ((gy & 7) == 0) {
            const int xcd = id & 7, slot = id >> 3;
            bn = slot % gx;
            bm = (xcd * (gy >> 3)) + slot / gx;
        } else { bm = blockIdx.y; bn = blockIdx.x; }
    }
    const long m0 = (long)bm * 256;
    const long n0 = (long)bn * 256;

    // Staging: one 16KB half per phase = 2 gld16/thread.
    // Lane l of wave w covers LDS row (rd*128 + w*16 + (l>>2)), 16B-block
    // (l&3); LDS offset = rd*8192 + w*1024 + l*16 (linear per wave, DMA-ok).
    // Bank swizzle: LDS block b of row r holds global k-block b^((r>>1)&3)
    // -> source k-block = (l&3) ^ ((l>>3)&3). Reads un-XOR it.
    const int srow = lane >> 2;                          // 0..15
    const int sk   = ((lane & 3) ^ ((lane >> 3) & 3)) * 8;
    const u16* gA = A + (m0 + wave * 16 + srow) * (long)lda + sk;
    const u16* gB = W + (n0 + wave * 16 + srow) * (long)K + sk;
    const long rdA2 = 128 * (long)lda;
    const long rdB2 = 128 * (long)K;

#define STA(sl, t, ks) do { const u16* g_ = gA + (t) * 64 + (ks) * 32; \
    gld16(g_,        &sA[sl][wave * 512]); \
    gld16(g_ + rdA2, &sA[sl][4096 + wave * 512]); } while (0)
#define STB(sl, t, ks) do { const u16* g_ = gB + (t) * 64 + (ks) * 32; \
    gld16(g_,        &sB[sl][wave * 512]); \
    gld16(g_ + rdB2, &sB[sl][4096 + wave * 512]); } while (0)

    const int quad = lane >> 4;    // 0..3 -> k = quad*8 + j
    const int l16  = lane & 15;    // m (A) / n (B) index within fragment
    const int koff = (quad ^ ((l16 >> 1) & 3)) << 4;     // un-swizzled 16B blk
    __attribute__((address_space(3))) const u16* baseA3 =
        (__attribute__((address_space(3))) const u16*)
        ((const char*)&sA[0][0] + wm * 8192 + l16 * 64 + koff);
    __attribute__((address_space(3))) const u16* baseB3 =
        (__attribute__((address_space(3))) const u16*)
        ((const char*)&sB[0][0] + wn * 4096 + l16 * 64 + koff);

    f32x4 acc[8][4];
#pragma unroll
    for (int i = 0; i < 8; i++)
#pragma unroll
        for (int j = 0; j < 4; j++) {
            f32x4 z = {0.f, 0.f, 0.f, 0.f};
            acc[i][j] = z;
        }
    // double-buffered fragment sets (static names; no runtime indexing)
    bf16x8 a0_0, a0_1, a0_2, a0_3;   // A set 0
    bf16x8 a1_0, a1_1, a1_2, a1_3;   // A set 1
    bf16x8 b0_0, b0_1, b0_2, b0_3;   // B set 0
    bf16x8 b1_0, b1_1, b1_2, b1_3;   // B set 1

// asm ds_read: invisible to the backend's waitcnt pass; completion governed
// solely by our counted lgkmcnt (rule 18: fence with sched_barrier).
#define DSR(dst, base, off) \
    asm volatile("ds_read_b128 %0, %1 offset:%2" \
                 : "=v"(dst) : "v"(base), "i"(off))
#define RDA(S, SLA, MQ) do { \
    DSR(a##S##_0, baseA3, (SLA) * 16384 + (MQ) * 4096 + 0);    \
    DSR(a##S##_1, baseA3, (SLA) * 16384 + (MQ) * 4096 + 1024); \
    DSR(a##S##_2, baseA3, (SLA) * 16384 + (MQ) * 4096 + 2048); \
    DSR(a##S##_3, baseA3, (SLA) * 16384 + (MQ) * 4096 + 3072); \
  } while (0)
#define RDB(S, SLB) do { \
    DSR(b##S##_0, baseB3, (SLB) * 16384 + 0);    \
    DSR(b##S##_1, baseB3, (SLB) * 16384 + 1024); \
    DSR(b##S##_2, baseB3, (SLB) * 16384 + 2048); \
    DSR(b##S##_3, baseB3, (SLB) * 16384 + 3072); \
  } while (0)

#define MM16(AS, BS, MQ) do { \
    acc[(MQ)*4+0][0] = __builtin_amdgcn_mfma_f32_16x16x32_bf16(a##AS##_0, b##BS##_0, acc[(MQ)*4+0][0], 0, 0, 0); \
    acc[(MQ)*4+0][1] = __builtin_amdgcn_mfma_f32_16x16x32_bf16(a##AS##_0, b##BS##_1, acc[(MQ)*4+0][1], 0, 0, 0); \
    acc[(MQ)*4+0][2] = __builtin_amdgcn_mfma_f32_16x16x32_bf16(a##AS##_0, b##BS##_2, acc[(MQ)*4+0][2], 0, 0, 0); \
    acc[(MQ)*4+0][3] = __builtin_amdgcn_mfma_f32_16x16x32_bf16(a##AS##_0, b##BS##_3, acc[(MQ)*4+0][3], 0, 0, 0); \
    acc[(MQ)*4+1][0] = __builtin_amdgcn_mfma_f32_16x16x32_bf16(a##AS##_1, b##BS##_0, acc[(MQ)*4+1][0], 0, 0, 0); \
    acc[(MQ)*4+1][1] = __builtin_amdgcn_mfma_f32_16x16x32_bf16(a##AS##_1, b##BS##_1, acc[(MQ)*4+1][1], 0, 0, 0); \
    acc[(MQ)*4+1][2] = __builtin_amdgcn_mfma_f32_16x16x32_bf16(a##AS##_1, b##BS##_2, acc[(MQ)*4+1][2], 0, 0, 0); \
    acc[(MQ)*4+1][3] = __builtin_amdgcn_mfma_f32_16x16x32_bf16(a##AS##_1, b##BS##_3, acc[(MQ)*4+1][3], 0, 0, 0); \
    acc[(MQ)*4+2][0] = __builtin_amdgcn_mfma_f32_16x16x32_bf16(a##AS##_2, b##BS##_0, acc[(MQ)*4+2][0], 0, 0, 0); \
    acc[(MQ)*4+2][1] = __builtin_amdgcn_mfma_f32_16x16x32_bf16(a##AS##_2, b##BS##_1, acc[(MQ)*4+2][1], 0, 0, 0); \
    acc[(MQ)*4+2][2] = __builtin_amdgcn_mfma_f32_16x16x32_bf16(a##AS##_2, b##BS##_2, acc[(MQ)*4+2][2], 0, 0, 0); \
    acc[(MQ)*4+2][3] = __builtin_amdgcn_mfma_f32_16x16x32_bf16(a##AS##_2, b##BS##_3, acc[(MQ)*4+2][3], 0, 0, 0); \
    acc[(MQ)*4+3][0] = __builtin_amdgcn_mfma_f32_16x16x32_bf16(a##AS##_3, b##BS##_0, acc[(MQ)*4+3][0], 0, 0, 0); \
    acc[(MQ)*4+3][1] = __builtin_amdgcn_mfma_f32_16x16x32_bf16(a##AS##_3, b##BS##_1, acc[(MQ)*4+3][1], 0, 0, 0); \
    acc[(MQ)*4+3][2] = __builtin_amdgcn_mfma_f32_16x16x32_bf16(a##AS##_3, b##BS##_2, acc[(MQ)*4+3][2], 0, 0, 0); \
    acc[(MQ)*4+3][3] = __builtin_amdgcn_mfma_f32_16x16x32_bf16(a##AS##_3, b##BS##_3, acc[(MQ)*4+3][3], 0, 0, 0); \
  } while (0)

// phase top: optional slot-verify vmcnt, the ONE barrier, pin reads after it.
#define PH_TOP0 do { \
    __builtin_amdgcn_s_barrier(); \
    __builtin_amdgcn_sched_barrier(0); } while (0)
#define PH_TOP1 do { \
    asm volatile("s_waitcnt vmcnt(6)" ::: "memory"); \
    __builtin_amdgcn_s_barrier(); \
    __builtin_amdgcn_sched_barrier(0); } while (0)
// phase bottom: counted lgkm (this phase's frags done, next phase's in
// flight), fence (rule 18), MFMA cluster under setprio.
#define PH_BOT(LGK, AS, BS, MQ) do { \
    asm volatile("s_waitcnt lgkmcnt(%0)" :: "i"(LGK) : "memory"); \
    __builtin_amdgcn_sched_barrier(0); \
    __builtin_amdgcn_s_setprio(1); \
    MM16(AS, BS, MQ); \
    __builtin_amdgcn_s_setprio(0); } while (0)

    const int nt = K >> 6;     // 64-wide K-tiles; nt even, >= 4 (K >= 256)
    // Prologue: stage slots A0,B0,A1,B1,A2,B2 (12 loads); land A0,B0;
    // issue phase-1 fragments (A slot0 mq0 + B slot0).
    STA(0, 0, 0); STB(0, 0, 0);
    STA(1, 0, 1); STB(1, 0, 1);
    STA(2, 1, 0); STB(2, 1, 0);
    asm volatile("s_waitcnt vmcnt(8)" ::: "memory");
    __builtin_amdgcn_s_barrier();
    __builtin_amdgcn_sched_barrier(0);
    RDA(0, 0, 0); RDB(0, 0);

    for (int T = 0; T < nt; T += 2) {
        const int t2 = (T + 2 < nt) ? T + 2 : 0;   // tail: wrap-stage (reads
        const int t3 = (T + 3 < nt) ? T + 3 : 1;   // of wrap land in dead regs)
        // Ph1 (T,0,0)
        PH_TOP0; RDA(1, 0, 1);            STA(3, T + 1, 1); PH_BOT(4, 0, 0, 0);
        // Ph2 (T,0,1)
        PH_TOP1; RDA(0, 1, 0); RDB(1, 1); STB(3, T + 1, 1); PH_BOT(8, 1, 0, 1);
        // Ph3 (T,1,0)
        PH_TOP0; RDA(1, 1, 1);            STA(0, t2, 0);    PH_BOT(4, 0, 1, 0);
        // Ph4 (T,1,1)
        PH_TOP1; RDA(0, 2, 0); RDB(0, 2); STB(0, t2, 0);    PH_BOT(8, 1, 1, 1);
        // Ph5 (T+1,0,0)
        PH_TOP0; RDA(1, 2, 1);            STA(1, t2, 1);    PH_BOT(4, 0, 0, 0);
        // Ph6 (T+1,0,1)
        PH_TOP1; RDA(0, 3, 0); RDB(1, 3); STB(1, t2, 1);    PH_BOT(8, 1, 0, 1);
        // Ph7 (T+1,1,0)
        PH_TOP0; RDA(1, 3, 1);            STA(2, t3, 0);    PH_BOT(4, 0, 1, 0);
        // Ph8 (T+1,1,1)
        PH_TOP1; RDA(0, 0, 0); RDB(0, 0); STB(2, t3, 0);    PH_BOT(8, 1, 1, 1);
    }
    // drain: late LDS returns must not clobber reallocated VGPRs.
    asm volatile("s_waitcnt lgkmcnt(0)" ::: "memory");
    __builtin_amdgcn_sched_barrier(0);

    // epilogue: C/D layout col = lane&15, row = quad*4 + reg  [m89/m91]
#pragma unroll
    for (int mt = 0; mt < 8; mt++) {
#pragma unroll
        for (int nf = 0; nf < 4; nf++) {
            const long col = n0 + wn * 64 + nf * 16 + l16;
            const float bv = bias ? bias[col] : 0.0f;
            const float gc = mode ? cg[col] : 0.0f;
            const float bc = (mode == 2) ? cb2[col] : 0.0f;
#pragma unroll
            for (int rr = 0; rr < 4; rr++) {
                const long row = m0 + wm * 128 + mt * 16 + quad * 4 + rr;
                float v = acc[mt][nf][rr];
                if (mode == 1) {
                    v = rowI[row] * (v - rowM[row] * gc) + bv;
                } else {
                    v += bv;
                    if (R)  v += R[row * (long)ldr + col];
                    if (Rb) {
                        float rb = bf2f(Rb[row * (long)ldrb + col]);
                        if (mode == 2)
                            v += (rb - rowM[row]) * rowI[row] * gc + bc;
                        else
                            v += rb;
                    }
                }
                if (do_gelu) v = gelu_f(v);
                if (Cf) Cf[row * (long)ldcf + col] = v;
                if (Cb) Cb[row * (long)ldcb + col] = f2bf(v);
            }
        }
    }
#undef PH_TOP0
#undef PH_TOP1
#undef PH_BOT
#undef MM16
#undef RDA
#undef RDB
#undef DSR
#undef STA
#undef STB
}

// LayerNorm over 768 cols, one block/row. Input bf16 (Xb) or f32 (Xf);
// output f32 (Yf) and/or bf16 (Yb); optional gelu. 192 active lanes x 4 elems.
__global__ void __launch_bounds__(256) ln_k(
    const u16*  __restrict__ Xb,
    const float* __restrict__ Xf,
    const float* __restrict__ g,
    const float* __restrict__ b,
    float* __restrict__ Yf,
    u16*   __restrict__ Yb,
    int do_gelu)
{
    const int row = blockIdx.x;
    const int tid = threadIdx.x;
    float v[4] = {0.f, 0.f, 0.f, 0.f};
    if (tid < 192) {
        if (Xb) {
            ushort4 u = ((const ushort4*)(Xb + (long)row * EDIM))[tid];
            v[0] = bf2f(u.x); v[1] = bf2f(u.y); v[2] = bf2f(u.z); v[3] = bf2f(u.w);
        } else {
            float4 f = ((const float4*)(Xf + (long)row * EDIM))[tid];
            v[0] = f.x; v[1] = f.y; v[2] = f.z; v[3] = f.w;
        }
    }
    float s = 0.f, s2 = 0.f;
#pragma unroll
    for (int j = 0; j < 4; j++) { s += v[j]; s2 += v[j] * v[j]; }
#pragma unroll
    for (int o = 32; o > 0; o >>= 1) {
        s  += __shfl_down(s,  o, 64);
        s2 += __shfl_down(s2, o, 64);
    }
    __shared__ float red[8];
    __shared__ float mb[2];
    const int wave = tid >> 6, lane = tid & 63;
    if (lane == 0) { red[wave] = s; red[4 + wave] = s2; }
    __syncthreads();
    if (tid == 0) {
        float S  = red[0] + red[1] + red[2] + red[3];
        float S2 = red[4] + red[5] + red[6] + red[7];
        float mean = S * (1.0f / 768.0f);
        float var  = S2 * (1.0f / 768.0f) - mean * mean;
        mb[0] = mean;
        mb[1] = rsqrtf(var + 1e-5f);
    }
    __syncthreads();
    if (tid < 192) {
        const float mean = mb[0], inv = mb[1];
        float y[4];
#pragma unroll
        for (int j = 0; j < 4; j++) {
            const int c = tid * 4 + j;
            y[j] = (v[j] - mean) * inv * g[c] + b[c];
            if (do_gelu) y[j] = gelu_f(y[j]);
        }
        if (Yf) {
            float4 o = {y[0], y[1], y[2], y[3]};
            ((float4*)(Yf + (long)row * EDIM))[tid] = o;
        }
        if (Yb) {
            ushort4 o = {f2bf(y[0]), f2bf(y[1]), f2bf(y[2]), f2bf(y[3])};
            ((ushort4*)(Yb + (long)row * EDIM))[tid] = o;
        }
    }
}

extern "C" void kernel_launch(void* const* d_in, const int* in_sizes, int n_in,
                              void* d_out, int out_size, void* d_ws, size_t ws_size,
                              hipStream_t stream) {
    (void)in_sizes; (void)n_in; (void)out_size;
    const float* image    = (const float*)d_in[0];
    const float* text     = (const float*)d_in[1];
    const float* it_Wv    = (const float*)d_in[4];
    const float* it_Wo    = (const float*)d_in[5];
    const float* it_bv    = (const float*)d_in[8];
    const float* it_bo    = (const float*)d_in[9];
    const float* ti_Wv    = (const float*)d_in[12];
    const float* ti_Wo    = (const float*)d_in[13];
    const float* ti_bv    = (const float*)d_in[16];
    const float* ti_bo    = (const float*)d_in[17];
    const float* ln_img_g = (const float*)d_in[18];
    const float* ln_img_b = (const float*)d_in[19];
    const float* ln_txt_g = (const float*)d_in[20];
    const float* ln_txt_b = (const float*)d_in[21];
    const float* fp_ln_g  = (const float*)d_in[22];
    const float* fp_ln_b  = (const float*)d_in[23];
    const float* fi_W1    = (const float*)d_in[24];
    const float* fi_b1    = (const float*)d_in[25];
    const float* fi_W2    = (const float*)d_in[26];
    const float* fi_b2    = (const float*)d_in[27];
    const float* ft_W1    = (const float*)d_in[28];
    const float* ft_b1    = (const float*)d_in[29];
    const float* ft_W2    = (const float*)d_in[30];
    const float* ft_b2    = (const float*)d_in[31];
    const float* fp_W     = (const float*)d_in[32];
    const float* fp_b     = (const float*)d_in[33];

    char* ws = (char*)d_ws;
    size_t off = 0;
    auto alloc = [&](size_t bytes) {
        char* p = ws + off; off += (bytes + 255) & ~(size_t)255; return p;
    };
    // bf16 weights (~28 MB, live whole call)
    u16* wo_it = (u16*)alloc((size_t)768 * 768 * 2);
    u16* wvT_it= (u16*)alloc((size_t)768 * 768 * 2);
    u16* wc_it = (u16*)alloc((size_t)768 * 768 * 2);
    u16* wo_ti = (u16*)alloc((size_t)768 * 768 * 2);
    u16* wvT_ti= (u16*)alloc((size_t)768 * 768 * 2);
    u16* wc_ti = (u16*)alloc((size_t)768 * 768 * 2);
    u16* w1i   = (u16*)alloc((size_t)3072 * 768 * 2);   // g-scaled (LN fused)
    u16* w2i   = (u16*)alloc((size_t)768 * 3072 * 2);
    u16* w1t   = (u16*)alloc((size_t)3072 * 768 * 2);   // g-scaled (LN fused)
    u16* w2t   = (u16*)alloc((size_t)768 * 3072 * 2);
    u16* wp    = (u16*)alloc((size_t)768 * 1536 * 2);
    float* bc_it = (float*)alloc(768 * 4);
    float* bc_ti = (float*)alloc(768 * 4);
    float* sg_i  = (float*)alloc(3072 * 4);
    float* bb_i  = (float*)alloc(3072 * 4);
    float* sg_t  = (float*)alloc(3072 * 4);
    float* bb_t  = (float*)alloc(3072 * 4);
    float* mrow  = (float*)alloc((size_t)BROWS * 4);
    float* irow  = (float*)alloc((size_t)BROWS * 4);
    // activations
    u16* pbuf  = (u16*)alloc((size_t)BROWS * 768 * 2);   // pre-LN bf16 (lives
                                                         // through FFN2 resid)
    u16* fused = (u16*)alloc((size_t)BROWS * 1536 * 2);  // [img | txt] bf16
    u16* text_bf = fused;     // alias: text_bf dead before fused is written
    // hbuf (FFN hidden, adaptive chunk)
    int fch = 16384;
    while (fch > 2048 && off + (size_t)fch * 3072 * 2 > ws_size) fch >>= 1;
    u16* hbuf = (u16*)alloc((size_t)fch * 3072 * 2);

    auto gemm = [&](const u16* A, int lda, const u16* W, int M, int N, int K,
                    const float* bias, const float* R, int ldr,
                    const u16* Rb, int ldrb,
                    const float* rM, const float* rI,
                    const float* cg, const float* cb2,
                    float* Cf, int ldcf, u16* Cb, int ldcb, int dg, int mode) {
        gemm_bt<<<dim3(N / 256, M / 256), dim3(512), 0, stream>>>(
            A, lda, W, bias, R, ldr, Rb, ldrb, rM, rI, cg, cb2,
            Cf, ldcf, Cb, ldcb, K, dg, mode);
    };
    // LN-fused FFN: x = pre-LN pbuf chunk; writes fused half (ld 1536).
    auto ffn = [&](const u16* xin, const u16* W1g, const float* sg,
                   const float* bb, const u16* W2, const float* b2,
                   const float* g, const float* b, u16* outp) {
        for (int c = 0; c < BROWS / fch; c++) {
            const u16* xc = xin + (size_t)c * fch * 768;
            const float* rM = mrow + (size_t)c * fch;
            const float* rI = irow + (size_t)c * fch;
            gemm(xc, 768, W1g, fch, 3072, 768, bb,
                 nullptr, 0, nullptr, 0, rM, rI, sg, nullptr,
                 nullptr, 0, hbuf, 3072, 1, 1);                 // mode 1 + gelu
            gemm(hbuf, 3072, W2, fch, 768, 3072, b2,
                 nullptr, 0, xc, 768, rM, rI, g, b,
                 nullptr, 0, outp + (size_t)c * fch * 1536, 1536, 0, 2); // mode 2
        }
    };

    // ---- conversions: one batched dispatch (fi_W1/ft_W1 g-scaled) ----
    ConvBatch cbt = { fi_W1, fi_W2, ft_W1, ft_W2, fp_W, it_Wo, ti_Wo, text,
                      w1i,   w2i,   w1t,   w2t,   wp,   wo_it, wo_ti, text_bf,
                      ln_img_g, ln_txt_g };
    conv8_k<<<dim3(CONV_BLOCKS), dim3(256), 0, stream>>>(cbt);
    // ---- weight combine: Wc = Wo@Wv (bf16), bc = Wo@bv + bo ----
    f32_to_bf16_T_k<<<dim3(24, 24), dim3(256), 0, stream>>>(it_Wv, wvT_it, 768, 768);
    f32_to_bf16_T_k<<<dim3(24, 24), dim3(256), 0, stream>>>(ti_Wv, wvT_ti, 768, 768);
    gemm128_k<<<dim3(6, 6), dim3(256), 0, stream>>>(wo_it, 768, wvT_it, wc_it, 768, 768);
    gemm128_k<<<dim3(6, 6), dim3(256), 0, stream>>>(wo_ti, 768, wvT_ti, wc_ti, 768, 768);
    bias_comb_k<<<dim3(192), dim3(256), 0, stream>>>(it_Wo, it_bv, it_bo, bc_it, 768);
    bias_comb_k<<<dim3(192), dim3(256), 0, stream>>>(ti_Wo, ti_bv, ti_bo, bc_ti, 768);
    // ---- LN-fusion constants: sg = W1@g, bb = W1@b + b1 ----
    sgbb_k<<<dim3(768), dim3(256), 0, stream>>>(fi_W1, ln_img_g, ln_img_b, fi_b1,
                                                sg_i, bb_i, 768);
    sgbb_k<<<dim3(768), dim3(256), 0, stream>>>(ft_W1, ln_txt_g, ln_txt_b, ft_b1,
                                                sg_t, bb_t, 768);

    // ---- image path: pre = text@Wc.T + bc + image; LN fused into FFN ----
    gemm(text_bf, 768, wc_it, BROWS, 768, 768, bc_it,
         image, 768, nullptr, 0, nullptr, nullptr, nullptr, nullptr,
         nullptr, 0, pbuf, 768, 0, 0);
    lnstats_k<<<dim3(BROWS / 4), dim3(256), 0, stream>>>(pbuf, mrow, irow);
    ffn(pbuf, w1i, sg_i, bb_i, w2i, fi_b2, ln_img_g, ln_img_b, fused);
    // ---- text path: kv = post-FFN img (fused left half) ----
    gemm(fused, 1536, wc_ti, BROWS, 768, 768, bc_ti,
         text, 768, nullptr, 0, nullptr, nullptr, nullptr, nullptr,
         nullptr, 0, pbuf, 768, 0, 0);
    lnstats_k<<<dim3(BROWS / 4), dim3(256), 0, stream>>>(pbuf, mrow, irow);
    ffn(pbuf, w1t, sg_t, bb_t, w2t, ft_b2, ln_txt_g, ln_txt_b, fused + 768);
    // ---- final projection + LN + gelu ----
    gemm(fused, 1536, wp, BROWS, 768, 1536, fp_b,
         nullptr, 0, nullptr, 0, nullptr, nullptr, nullptr, nullptr,
         nullptr, 0, pbuf, 768, 0, 0);
    ln_k<<<dim3(BROWS), dim3(256), 0, stream>>>(
        pbuf, nullptr, fp_ln_g, fp_ln_b, (float*)d_out, nullptr, 1);
}

// Round 6
// 1078.278 us; speedup vs baseline: 1.1135x; 1.1135x over previous
//
#include <hip/hip_runtime.h>
#include <hip/hip_bf16.h>
#include <math.h>

// CrossAttentionFusion on MI355X.
// softmax over one key == 1  =>  mha1(q_in, kv) = kv@Wc.T + bc,
//   Wc = Wo@Wv (fused once), bc = Wo@bv + bo.
// R11: R9 graph restored (LN fusion of R10 regressed: per-element rowM/rowI/
// sg loads in the scalar epilogue cost ~+40us x4 FFN GEMMs vs ~16us of ln_k
// savings). Kept from R10: the 768^3 weight combines on a dedicated 128^2
// 2-phase kernel (36 blocks, ~7us) instead of the 256^2 kernel (9 blocks,
// ~30us). Hot 256^2 8-phase loop frozen (R7-R9: ~845 TF/active-CU).

typedef unsigned short u16;
typedef __bf16 bf16_t;
typedef bf16_t bf16x8 __attribute__((ext_vector_type(8)));
typedef float f32x4 __attribute__((ext_vector_type(4)));

#define BROWS 16384   // batch
#define EDIM  768

__device__ __forceinline__ u16 f2bf(float f) {
    union { float f; unsigned u; } v; v.f = f;
    return (u16)((v.u + 0x7FFFu + ((v.u >> 16) & 1u)) >> 16);  // RNE
}
__device__ __forceinline__ float bf2f(u16 h) {
    union { unsigned u; float f; } v; v.u = ((unsigned)h) << 16;
    return v.f;
}
// gelu via x*sigmoid(1.5957691*x + 0.0713548*x^3); exp2/rcp HW instrs.
__device__ __forceinline__ float gelu_f(float x) {
    float t = x * x;
    float p = fmaf(0.102943268f, t, 2.30221895f);   // log2(e) folded in
    float e = __builtin_amdgcn_exp2f(-x * p);
    return x * __builtin_amdgcn_rcpf(1.0f + e);
}

// async global->LDS, 16B/lane. LDS dest is wave-uniform base + lane*16.
__device__ __forceinline__ void gld16(const u16* g, u16* l) {
    __builtin_amdgcn_global_load_lds(
        (__attribute__((address_space(1))) void*)g,
        (__attribute__((address_space(3))) void*)l, 16, 0, 0);
}

// ---- batched f32->bf16 conversion: 8 tensors, one dispatch ----
struct ConvBatch {
    const float *s0, *s1, *s2, *s3, *s4, *s5, *s6, *s7;
    u16 *d0, *d1, *d2, *d3, *d4, *d5, *d6, *d7;
};
#define CB0 2304   // fi_W1 3072*768
#define CB1 2304   // fi_W2
#define CB2 2304   // ft_W1
#define CB3 2304   // ft_W2
#define CB4 1152   // fp_W 768*1536
#define CB5 576    // it_Wo 768*768
#define CB6 576    // ti_Wo
#define CB7 12288  // text 16384*768
#define CONV_BLOCKS (CB0+CB1+CB2+CB3+CB4+CB5+CB6+CB7)

__global__ void __launch_bounds__(256) conv8_k(ConvBatch cb) {
    int b = blockIdx.x;
    const float* s; u16* d;
    if      (b < CB0)          { s = cb.s0; d = cb.d0; }
    else if ((b -= CB0) < CB1) { s = cb.s1; d = cb.d1; }
    else if ((b -= CB1) < CB2) { s = cb.s2; d = cb.d2; }
    else if ((b -= CB2) < CB3) { s = cb.s3; d = cb.d3; }
    else if ((b -= CB3) < CB4) { s = cb.s4; d = cb.d4; }
    else if ((b -= CB4) < CB5) { s = cb.s5; d = cb.d5; }
    else if ((b -= CB5) < CB6) { s = cb.s6; d = cb.d6; }
    else    { b -= CB6;          s = cb.s7; d = cb.d7; }
    int i = b * 256 + threadIdx.x;
    float4 v = ((const float4*)s)[i];
    ushort4 o;
    o.x = f2bf(v.x); o.y = f2bf(v.y); o.z = f2bf(v.z); o.w = f2bf(v.w);
    ((ushort4*)d)[i] = o;
}

// D[c,r] = bf16(S[r,c]) — transpose-convert (Wv.T for the weight combine).
__global__ void __launch_bounds__(256) f32_to_bf16_T_k(const float* __restrict__ S,
                                                       u16* __restrict__ D,
                                                       int R, int C) {
    __shared__ float t[32][33];
    const int r0 = blockIdx.y * 32, c0 = blockIdx.x * 32;
    const int tx = threadIdx.x & 31, ty = threadIdx.x >> 5;  // ty 0..7
#pragma unroll
    for (int i = ty; i < 32; i += 8) t[i][tx] = S[(long)(r0 + i) * C + c0 + tx];
    __syncthreads();
#pragma unroll
    for (int i = ty; i < 32; i += 8) D[(long)(c0 + i) * R + r0 + tx] = f2bf(t[tx][i]);
}

// bc[n] = bo[n] + dot(Wo[n,:], bv)
__global__ void __launch_bounds__(256) bias_comb_k(const float* __restrict__ Wo,
                                                   const float* __restrict__ bv,
                                                   const float* __restrict__ bo,
                                                   float* __restrict__ bc, int K) {
    const int n = blockIdx.x * 4 + (threadIdx.x >> 6);
    const int lane = threadIdx.x & 63;
    float s = 0.f;
    for (int k = lane; k < K; k += 64) s += Wo[(long)n * K + k] * bv[k];
#pragma unroll
    for (int o = 32; o > 0; o >>= 1) s += __shfl_down(s, o, 64);
    if (lane == 0) bc[n] = s + bo[n];
}

// ---- small GEMM (128x128 tile, BK=32, 2-phase, 4 waves) for the 768^3
// weight combines. R5-verified structure; harness-verified in R10.
__global__ void __launch_bounds__(256) gemm128_k(
    const u16* __restrict__ A, int lda,
    const u16* __restrict__ W,
    u16* __restrict__ Cb, int ldcb, int K)
{
    __shared__ alignas(16) u16 sA[2][128 * 32];
    __shared__ alignas(16) u16 sB[2][128 * 32];
    const int tid  = threadIdx.x;
    const int lane = tid & 63;
    const int wave = tid >> 6;
    const int wm = wave >> 1, wn = wave & 1;
    const long m0 = (long)blockIdx.y * 128;
    const long n0 = (long)blockIdx.x * 128;
    const int r   = lane >> 2;
    const int cbk = lane & 3;
    const int cbs = cbk ^ ((r >> 1) & 3);
    const int c0 = wave * 2, c1 = wave * 2 + 1;
    const u16* gA0 = A + (m0 + c0 * 16 + r) * (long)lda + cbs * 8;
    const u16* gA1 = A + (m0 + c1 * 16 + r) * (long)lda + cbs * 8;
    const u16* gB0 = W + (n0 + c0 * 16 + r) * (long)K + cbs * 8;
    const u16* gB1 = W + (n0 + c1 * 16 + r) * (long)K + cbs * 8;
    auto stage = [&](int buf, int kk) {
        gld16(gA0 + kk, sA[buf] + c0 * 512);
        gld16(gA1 + kk, sA[buf] + c1 * 512);
        gld16(gB0 + kk, sB[buf] + c0 * 512);
        gld16(gB1 + kk, sB[buf] + c1 * 512);
    };
    const int quad = lane >> 4;
    const int l16  = lane & 15;
    int offA[4], offB[4];
#pragma unroll
    for (int t = 0; t < 4; t++) {
        const int rowA = wm * 64 + t * 16 + l16;
        const int rowB = wn * 64 + t * 16 + l16;
        offA[t] = rowA * 32 + (quad ^ ((rowA >> 1) & 3)) * 8;
        offB[t] = rowB * 32 + (quad ^ ((rowB >> 1) & 3)) * 8;
    }
    f32x4 acc[4][4];
#pragma unroll
    for (int i = 0; i < 4; i++)
#pragma unroll
        for (int j = 0; j < 4; j++) {
            f32x4 z = {0.f, 0.f, 0.f, 0.f};
            acc[i][j] = z;
        }
    stage(0, 0);
    __syncthreads();
    int buf = 0;
    for (int k0 = 0; k0 < K; k0 += 32) {
        const int nk = k0 + 32;
        if (nk < K) stage(buf ^ 1, nk);
        bf16x8 af[4], bfr[4];
#pragma unroll
        for (int t = 0; t < 4; t++) af[t]  = *(const bf16x8*)(sA[buf] + offA[t]);
#pragma unroll
        for (int t = 0; t < 4; t++) bfr[t] = *(const bf16x8*)(sB[buf] + offB[t]);
#pragma unroll
        for (int mt = 0; mt < 4; mt++)
#pragma unroll
            for (int nt = 0; nt < 4; nt++)
                acc[mt][nt] = __builtin_amdgcn_mfma_f32_16x16x32_bf16(
                    af[mt], bfr[nt], acc[mt][nt], 0, 0, 0);
        __syncthreads();
        buf ^= 1;
    }
#pragma unroll
    for (int mt = 0; mt < 4; mt++)
#pragma unroll
        for (int nt = 0; nt < 4; nt++) {
            const long col = n0 + wn * 64 + nt * 16 + l16;
#pragma unroll
            for (int rr = 0; rr < 4; rr++) {
                const long row = m0 + wm * 64 + mt * 16 + quad * 4 + rr;
                Cb[row * (long)ldcb + col] = f2bf(acc[mt][nt][rr]);
            }
        }
}

// C[m,n] = sum_k A[m,k] * W[n,k]  (+bias, +f32 or bf16 residual, opt gelu)
// 256x256 tile, 8 waves (2M x 4N), per-wave C = 128x64. One barrier/phase,
// fragment reads pipelined one phase ahead (counted lgkmcnt). (R9 loop.)
__global__ void __launch_bounds__(512, 2) gemm_bt(
    const u16* __restrict__ A, int lda,
    const u16* __restrict__ W,
    const float* __restrict__ bias,
    const float* __restrict__ R, int ldr,      // f32 residual (or null)
    const u16* __restrict__ Rb, int ldrb,      // bf16 residual (or null)
    float* __restrict__ Cf, int ldcf,
    u16* __restrict__ Cb, int ldcb,
    int K, int do_gelu)
{
    __shared__ alignas(16) u16 sA[4][256 * 32];   // 4 k-half slots x 16KB
    __shared__ alignas(16) u16 sB[4][256 * 32];

    const int tid  = threadIdx.x;
    const int lane = tid & 63;
    const int wave = tid >> 6;     // 0..7
    const int wm = wave >> 2;      // 0..1  (M half)
    const int wn = wave & 3;       // 0..3  (N quarter)

    // XCD-aware swizzle: id%8 = XCD (round-robin dispatch). Give each XCD a
    // contiguous slab of row-tiles; sweep col-tiles fastest within the slab.
    int bm, bn;
    {
        const int gx = gridDim.x, gy = gridDim.y;
        const int id = blockIdx.y * gx + blockIdx.x;
        if ((gy & 7) == 0) {
            const int xcd = id & 7, slot = id >> 3;
            bn = slot % gx;
            bm = (xcd * (gy >> 3)) + slot / gx;
        } else { bm = blockIdx.y; bn = blockIdx.x; }
    }
    const long m0 = (long)bm * 256;
    const long n0 = (long)bn * 256;

    // Staging: one 16KB half per phase = 2 gld16/thread.
    // Lane l of wave w covers LDS row (rd*128 + w*16 + (l>>2)), 16B-block
    // (l&3); LDS offset = rd*8192 + w*1024 + l*16 (linear per wave, DMA-ok).
    // Bank swizzle: LDS block b of row r holds global k-block b^((r>>1)&3)
    // -> source k-block = (l&3) ^ ((l>>3)&3). Reads un-XOR it.
    const int srow = lane >> 2;                          // 0..15
    const int sk   = ((lane & 3) ^ ((lane >> 3) & 3)) * 8;
    const u16* gA = A + (m0 + wave * 16 + srow) * (long)lda + sk;
    const u16* gB = W + (n0 + wave * 16 + srow) * (long)K + sk;
    const long rdA2 = 128 * (long)lda;
    const long rdB2 = 128 * (long)K;

#define STA(sl, t, ks) do { const u16* g_ = gA + (t) * 64 + (ks) * 32; \
    gld16(g_,        &sA[sl][wave * 512]); \
    gld16(g_ + rdA2, &sA[sl][4096 + wave * 512]); } while (0)
#define STB(sl, t, ks) do { const u16* g_ = gB + (t) * 64 + (ks) * 32; \
    gld16(g_,        &sB[sl][wave * 512]); \
    gld16(g_ + rdB2, &sB[sl][4096 + wave * 512]); } while (0)

    const int quad = lane >> 4;    // 0..3 -> k = quad*8 + j
    const int l16  = lane & 15;    // m (A) / n (B) index within fragment
    const int koff = (quad ^ ((l16 >> 1) & 3)) << 4;     // un-swizzled 16B blk
    __attribute__((address_space(3))) const u16* baseA3 =
        (__attribute__((address_space(3))) const u16*)
        ((const char*)&sA[0][0] + wm * 8192 + l16 * 64 + koff);
    __attribute__((address_space(3))) const u16* baseB3 =
        (__attribute__((address_space(3))) const u16*)
        ((const char*)&sB[0][0] + wn * 4096 + l16 * 64 + koff);

    f32x4 acc[8][4];
#pragma unroll
    for (int i = 0; i < 8; i++)
#pragma unroll
        for (int j = 0; j < 4; j++) {
            f32x4 z = {0.f, 0.f, 0.f, 0.f};
            acc[i][j] = z;
        }
    // double-buffered fragment sets (static names; no runtime indexing)
    bf16x8 a0_0, a0_1, a0_2, a0_3;   // A set 0
    bf16x8 a1_0, a1_1, a1_2, a1_3;   // A set 1
    bf16x8 b0_0, b0_1, b0_2, b0_3;   // B set 0
    bf16x8 b1_0, b1_1, b1_2, b1_3;   // B set 1

// asm ds_read: invisible to the backend's waitcnt pass; completion governed
// solely by our counted lgkmcnt (rule 18: fence with sched_barrier).
#define DSR(dst, base, off) \
    asm volatile("ds_read_b128 %0, %1 offset:%2" \
                 : "=v"(dst) : "v"(base), "i"(off))
#define RDA(S, SLA, MQ) do { \
    DSR(a##S##_0, baseA3, (SLA) * 16384 + (MQ) * 4096 + 0);    \
    DSR(a##S##_1, baseA3, (SLA) * 16384 + (MQ) * 4096 + 1024); \
    DSR(a##S##_2, baseA3, (SLA) * 16384 + (MQ) * 4096 + 2048); \
    DSR(a##S##_3, baseA3, (SLA) * 16384 + (MQ) * 4096 + 3072); \
  } while (0)
#define RDB(S, SLB) do { \
    DSR(b##S##_0, baseB3, (SLB) * 16384 + 0);    \
    DSR(b##S##_1, baseB3, (SLB) * 16384 + 1024); \
    DSR(b##S##_2, baseB3, (SLB) * 16384 + 2048); \
    DSR(b##S##_3, baseB3, (SLB) * 16384 + 3072); \
  } while (0)

#define MM16(AS, BS, MQ) do { \
    acc[(MQ)*4+0][0] = __builtin_amdgcn_mfma_f32_16x16x32_bf16(a##AS##_0, b##BS##_0, acc[(MQ)*4+0][0], 0, 0, 0); \
    acc[(MQ)*4+0][1] = __builtin_amdgcn_mfma_f32_16x16x32_bf16(a##AS##_0, b##BS##_1, acc[(MQ)*4+0][1], 0, 0, 0); \
    acc[(MQ)*4+0][2] = __builtin_amdgcn_mfma_f32_16x16x32_bf16(a##AS##_0, b##BS##_2, acc[(MQ)*4+0][2], 0, 0, 0); \
    acc[(MQ)*4+0][3] = __builtin_amdgcn_mfma_f32_16x16x32_bf16(a##AS##_0, b##BS##_3, acc[(MQ)*4+0][3], 0, 0, 0); \
    acc[(MQ)*4+1][0] = __builtin_amdgcn_mfma_f32_16x16x32_bf16(a##AS##_1, b##BS##_0, acc[(MQ)*4+1][0], 0, 0, 0); \
    acc[(MQ)*4+1][1] = __builtin_amdgcn_mfma_f32_16x16x32_bf16(a##AS##_1, b##BS##_1, acc[(MQ)*4+1][1], 0, 0, 0); \
    acc[(MQ)*4+1][2] = __builtin_amdgcn_mfma_f32_16x16x32_bf16(a##AS##_1, b##BS##_2, acc[(MQ)*4+1][2], 0, 0, 0); \
    acc[(MQ)*4+1][3] = __builtin_amdgcn_mfma_f32_16x16x32_bf16(a##AS##_1, b##BS##_3, acc[(MQ)*4+1][3], 0, 0, 0); \
    acc[(MQ)*4+2][0] = __builtin_amdgcn_mfma_f32_16x16x32_bf16(a##AS##_2, b##BS##_0, acc[(MQ)*4+2][0], 0, 0, 0); \
    acc[(MQ)*4+2][1] = __builtin_amdgcn_mfma_f32_16x16x32_bf16(a##AS##_2, b##BS##_1, acc[(MQ)*4+2][1], 0, 0, 0); \
    acc[(MQ)*4+2][2] = __builtin_amdgcn_mfma_f32_16x16x32_bf16(a##AS##_2, b##BS##_2, acc[(MQ)*4+2][2], 0, 0, 0); \
    acc[(MQ)*4+2][3] = __builtin_amdgcn_mfma_f32_16x16x32_bf16(a##AS##_2, b##BS##_3, acc[(MQ)*4+2][3], 0, 0, 0); \
    acc[(MQ)*4+3][0] = __builtin_amdgcn_mfma_f32_16x16x32_bf16(a##AS##_3, b##BS##_0, acc[(MQ)*4+3][0], 0, 0, 0); \
    acc[(MQ)*4+3][1] = __builtin_amdgcn_mfma_f32_16x16x32_bf16(a##AS##_3, b##BS##_1, acc[(MQ)*4+3][1], 0, 0, 0); \
    acc[(MQ)*4+3][2] = __builtin_amdgcn_mfma_f32_16x16x32_bf16(a##AS##_3, b##BS##_2, acc[(MQ)*4+3][2], 0, 0, 0); \
    acc[(MQ)*4+3][3] = __builtin_amdgcn_mfma_f32_16x16x32_bf16(a##AS##_3, b##BS##_3, acc[(MQ)*4+3][3], 0, 0, 0); \
  } while (0)

// phase top: optional slot-verify vmcnt, the ONE barrier, pin reads after it.
#define PH_TOP0 do { \
    __builtin_amdgcn_s_barrier(); \
    __builtin_amdgcn_sched_barrier(0); } while (0)
#define PH_TOP1 do { \
    asm volatile("s_waitcnt vmcnt(6)" ::: "memory"); \
    __builtin_amdgcn_s_barrier(); \
    __builtin_amdgcn_sched_barrier(0); } while (0)
// phase bottom: counted lgkm (this phase's frags done, next phase's in
// flight), fence (rule 18), MFMA cluster under setprio.
#define PH_BOT(LGK, AS, BS, MQ) do { \
    asm volatile("s_waitcnt lgkmcnt(%0)" :: "i"(LGK) : "memory"); \
    __builtin_amdgcn_sched_barrier(0); \
    __builtin_amdgcn_s_setprio(1); \
    MM16(AS, BS, MQ); \
    __builtin_amdgcn_s_setprio(0); } while (0)

    const int nt = K >> 6;     // 64-wide K-tiles; nt even, >= 4 (K >= 256)
    // Prologue: stage slots A0,B0,A1,B1,A2,B2 (12 loads); land A0,B0;
    // issue phase-1 fragments (A slot0 mq0 + B slot0).
    STA(0, 0, 0); STB(0, 0, 0);
    STA(1, 0, 1); STB(1, 0, 1);
    STA(2, 1, 0); STB(2, 1, 0);
    asm volatile("s_waitcnt vmcnt(8)" ::: "memory");
    __builtin_amdgcn_s_barrier();
    __builtin_amdgcn_sched_barrier(0);
    RDA(0, 0, 0); RDB(0, 0);

    for (int T = 0; T < nt; T += 2) {
        const int t2 = (T + 2 < nt) ? T + 2 : 0;   // tail: wrap-stage (reads
        const int t3 = (T + 3 < nt) ? T + 3 : 1;   // of wrap land in dead regs)
        // Ph1 (T,0,0)
        PH_TOP0; RDA(1, 0, 1);            STA(3, T + 1, 1); PH_BOT(4, 0, 0, 0);
        // Ph2 (T,0,1)
        PH_TOP1; RDA(0, 1, 0); RDB(1, 1); STB(3, T + 1, 1); PH_BOT(8, 1, 0, 1);
        // Ph3 (T,1,0)
        PH_TOP0; RDA(1, 1, 1);            STA(0, t2, 0);    PH_BOT(4, 0, 1, 0);
        // Ph4 (T,1,1)
        PH_TOP1; RDA(0, 2, 0); RDB(0, 2); STB(0, t2, 0);    PH_BOT(8, 1, 1, 1);
        // Ph5 (T+1,0,0)
        PH_TOP0; RDA(1, 2, 1);            STA(1, t2, 1);    PH_BOT(4, 0, 0, 0);
        // Ph6 (T+1,0,1)
        PH_TOP1; RDA(0, 3, 0); RDB(1, 3); STB(1, t2, 1);    PH_BOT(8, 1, 0, 1);
        // Ph7 (T+1,1,0)
        PH_TOP0; RDA(1, 3, 1);            STA(2, t3, 0);    PH_BOT(4, 0, 1, 0);
        // Ph8 (T+1,1,1)
        PH_TOP1; RDA(0, 0, 0); RDB(0, 0); STB(2, t3, 0);    PH_BOT(8, 1, 1, 1);
    }
    // drain: late LDS returns must not clobber reallocated VGPRs.
    asm volatile("s_waitcnt lgkmcnt(0)" ::: "memory");
    __builtin_amdgcn_sched_barrier(0);

    // epilogue: C/D layout col = lane&15, row = quad*4 + reg  [m89/m91]
#pragma unroll
    for (int mt = 0; mt < 8; mt++) {
#pragma unroll
        for (int nf = 0; nf < 4; nf++) {
            const long col = n0 + wn * 64 + nf * 16 + l16;
            const float bv = bias ? bias[col] : 0.0f;
#pragma unroll
            for (int rr = 0; rr < 4; rr++) {
                const long row = m0 + wm * 128 + mt * 16 + quad * 4 + rr;
                float v = acc[mt][nf][rr] + bv;
                if (R)  v += R[row * (long)ldr + col];
                if (Rb) v += bf2f(Rb[row * (long)ldrb + col]);
                if (do_gelu) v = gelu_f(v);
                if (Cf) Cf[row * (long)ldcf + col] = v;
                if (Cb) Cb[row * (long)ldcb + col] = f2bf(v);
            }
        }
    }
#undef PH_TOP0
#undef PH_TOP1
#undef PH_BOT
#undef MM16
#undef RDA
#undef RDB
#undef DSR
#undef STA
#undef STB
}

// LayerNorm over 768 cols, one block/row. Input bf16 (Xb) or f32 (Xf);
// output f32 (Yf) and/or bf16 (Yb); optional gelu. 192 active lanes x 4 elems.
__global__ void __launch_bounds__(256) ln_k(
    const u16*  __restrict__ Xb,
    const float* __restrict__ Xf,
    const float* __restrict__ g,
    const float* __restrict__ b,
    float* __restrict__ Yf,
    u16*   __restrict__ Yb,
    int do_gelu)
{
    const int row = blockIdx.x;
    const int tid = threadIdx.x;
    float v[4] = {0.f, 0.f, 0.f, 0.f};
    if (tid < 192) {
        if (Xb) {
            ushort4 u = ((const ushort4*)(Xb + (long)row * EDIM))[tid];
            v[0] = bf2f(u.x); v[1] = bf2f(u.y); v[2] = bf2f(u.z); v[3] = bf2f(u.w);
        } else {
            float4 f = ((const float4*)(Xf + (long)row * EDIM))[tid];
            v[0] = f.x; v[1] = f.y; v[2] = f.z; v[3] = f.w;
        }
    }
    float s = 0.f, s2 = 0.f;
#pragma unroll
    for (int j = 0; j < 4; j++) { s += v[j]; s2 += v[j] * v[j]; }
#pragma unroll
    for (int o = 32; o > 0; o >>= 1) {
        s  += __shfl_down(s,  o, 64);
        s2 += __shfl_down(s2, o, 64);
    }
    __shared__ float red[8];
    __shared__ float mb[2];
    const int wave = tid >> 6, lane = tid & 63;
    if (lane == 0) { red[wave] = s; red[4 + wave] = s2; }
    __syncthreads();
    if (tid == 0) {
        float S  = red[0] + red[1] + red[2] + red[3];
        float S2 = red[4] + red[5] + red[6] + red[7];
        float mean = S * (1.0f / 768.0f);
        float var  = S2 * (1.0f / 768.0f) - mean * mean;
        mb[0] = mean;
        mb[1] = rsqrtf(var + 1e-5f);
    }
    __syncthreads();
    if (tid < 192) {
        const float mean = mb[0], inv = mb[1];
        float y[4];
#pragma unroll
        for (int j = 0; j < 4; j++) {
            const int c = tid * 4 + j;
            y[j] = (v[j] - mean) * inv * g[c] + b[c];
            if (do_gelu) y[j] = gelu_f(y[j]);
        }
        if (Yf) {
            float4 o = {y[0], y[1], y[2], y[3]};
            ((float4*)(Yf + (long)row * EDIM))[tid] = o;
        }
        if (Yb) {
            ushort4 o = {f2bf(y[0]), f2bf(y[1]), f2bf(y[2]), f2bf(y[3])};
            ((ushort4*)(Yb + (long)row * EDIM))[tid] = o;
        }
    }
}

extern "C" void kernel_launch(void* const* d_in, const int* in_sizes, int n_in,
                              void* d_out, int out_size, void* d_ws, size_t ws_size,
                              hipStream_t stream) {
    (void)in_sizes; (void)n_in; (void)out_size;
    const float* image    = (const float*)d_in[0];
    const float* text     = (const float*)d_in[1];
    const float* it_Wv    = (const float*)d_in[4];
    const float* it_Wo    = (const float*)d_in[5];
    const float* it_bv    = (const float*)d_in[8];
    const float* it_bo    = (const float*)d_in[9];
    const float* ti_Wv    = (const float*)d_in[12];
    const float* ti_Wo    = (const float*)d_in[13];
    const float* ti_bv    = (const float*)d_in[16];
    const float* ti_bo    = (const float*)d_in[17];
    const float* ln_img_g = (const float*)d_in[18];
    const float* ln_img_b = (const float*)d_in[19];
    const float* ln_txt_g = (const float*)d_in[20];
    const float* ln_txt_b = (const float*)d_in[21];
    const float* fp_ln_g  = (const float*)d_in[22];
    const float* fp_ln_b  = (const float*)d_in[23];
    const float* fi_W1    = (const float*)d_in[24];
    const float* fi_b1    = (const float*)d_in[25];
    const float* fi_W2    = (const float*)d_in[26];
    const float* fi_b2    = (const float*)d_in[27];
    const float* ft_W1    = (const float*)d_in[28];
    const float* ft_b1    = (const float*)d_in[29];
    const float* ft_W2    = (const float*)d_in[30];
    const float* ft_b2    = (const float*)d_in[31];
    const float* fp_W     = (const float*)d_in[32];
    const float* fp_b     = (const float*)d_in[33];

    char* ws = (char*)d_ws;
    size_t off = 0;
    auto alloc = [&](size_t bytes) {
        char* p = ws + off; off += (bytes + 255) & ~(size_t)255; return p;
    };
    // bf16 weights (~28 MB, live whole call)
    u16* wo_it = (u16*)alloc((size_t)768 * 768 * 2);
    u16* wvT_it= (u16*)alloc((size_t)768 * 768 * 2);
    u16* wc_it = (u16*)alloc((size_t)768 * 768 * 2);
    u16* wo_ti = (u16*)alloc((size_t)768 * 768 * 2);
    u16* wvT_ti= (u16*)alloc((size_t)768 * 768 * 2);
    u16* wc_ti = (u16*)alloc((size_t)768 * 768 * 2);
    u16* w1i   = (u16*)alloc((size_t)3072 * 768 * 2);
    u16* w2i   = (u16*)alloc((size_t)768 * 3072 * 2);
    u16* w1t   = (u16*)alloc((size_t)3072 * 768 * 2);
    u16* w2t   = (u16*)alloc((size_t)768 * 3072 * 2);
    u16* wp    = (u16*)alloc((size_t)768 * 1536 * 2);
    float* bc_it = (float*)alloc(768 * 4);
    float* bc_ti = (float*)alloc(768 * 4);
    // activations
    u16* vbuf  = (u16*)alloc((size_t)BROWS * 768 * 2);   // post-LN bf16
    u16* fused = (u16*)alloc((size_t)BROWS * 1536 * 2);  // [img | txt] bf16
    u16* text_bf = fused;     // alias: text_bf dead before fused is written
    // hbuf (FFN hidden, adaptive chunk) and pbuf (bf16 pre-LN) share a region.
    int fch = 16384;
    while (fch > 2048 && off + (size_t)fch * 3072 * 2 > ws_size) fch >>= 1;
    size_t region = (size_t)fch * 3072 * 2;
    if (region < (size_t)BROWS * 768 * 2) region = (size_t)BROWS * 768 * 2;
    u16* hbuf = (u16*)alloc(region);
    u16* pbuf = hbuf;

    auto gemm = [&](const u16* A, int lda, const u16* W, int M, int N, int K,
                    const float* bias, const float* R, int ldr,
                    const u16* Rb, int ldrb,
                    float* Cf, int ldcf, u16* Cb, int ldcb, int dg) {
        gemm_bt<<<dim3(N / 256, M / 256), dim3(512), 0, stream>>>(
            A, lda, W, bias, R, ldr, Rb, ldrb, Cf, ldcf, Cb, ldcb, K, dg);
    };
    auto ffn = [&](const u16* xin, const u16* W1, const float* b1,
                   const u16* W2, const float* b2, u16* outp, int ldout) {
        for (int c = 0; c < BROWS / fch; c++) {
            const u16* xc = xin + (size_t)c * fch * 768;
            gemm(xc, 768, W1, fch, 3072, 768, b1,
                 nullptr, 0, nullptr, 0, nullptr, 0, hbuf, 3072, 1);
            gemm(hbuf, 3072, W2, fch, 768, 3072, b2,
                 nullptr, 0, xc, 768,
                 nullptr, 0, outp + (size_t)c * fch * ldout, ldout, 0);
        }
    };

    // ---- conversions: one batched dispatch ----
    ConvBatch cbt = { fi_W1, fi_W2, ft_W1, ft_W2, fp_W, it_Wo, ti_Wo, text,
                      w1i,   w2i,   w1t,   w2t,   wp,   wo_it, wo_ti, text_bf };
    conv8_k<<<dim3(CONV_BLOCKS), dim3(256), 0, stream>>>(cbt);
    // ---- weight combine: Wc = Wo@Wv (bf16), bc = Wo@bv + bo ----
    f32_to_bf16_T_k<<<dim3(24, 24), dim3(256), 0, stream>>>(it_Wv, wvT_it, 768, 768);
    f32_to_bf16_T_k<<<dim3(24, 24), dim3(256), 0, stream>>>(ti_Wv, wvT_ti, 768, 768);
    gemm128_k<<<dim3(6, 6), dim3(256), 0, stream>>>(wo_it, 768, wvT_it, wc_it, 768, 768);
    gemm128_k<<<dim3(6, 6), dim3(256), 0, stream>>>(wo_ti, 768, wvT_ti, wc_ti, 768, 768);
    bias_comb_k<<<dim3(192), dim3(256), 0, stream>>>(it_Wo, it_bv, it_bo, bc_it, 768);
    bias_comb_k<<<dim3(192), dim3(256), 0, stream>>>(ti_Wo, ti_bv, ti_bo, bc_ti, 768);

    // ---- image path: att = text@Wc.T + bc + image ; LN1 ----
    gemm(text_bf, 768, wc_it, BROWS, 768, 768, bc_it,
         image, 768, nullptr, 0, nullptr, 0, pbuf, 768, 0);
    ln_k<<<dim3(BROWS), dim3(256), 0, stream>>>(
        pbuf, nullptr, ln_img_g, ln_img_b, nullptr, vbuf, 0);
    ffn(vbuf, w1i, fi_b1, w2i, fi_b2, fused, 1536);   // -> fused[:, :768]
    // ---- text path: kv = post-FFN img (fused left half) ----
    gemm(fused, 1536, wc_ti, BROWS, 768, 768, bc_ti,
         text, 768, nullptr, 0, nullptr, 0, pbuf, 768, 0);
    ln_k<<<dim3(BROWS), dim3(256), 0, stream>>>(
        pbuf, nullptr, ln_txt_g, ln_txt_b, nullptr, vbuf, 0);
    ffn(vbuf, w1t, ft_b1, w2t, ft_b2, fused + 768, 1536);  // -> fused[:, 768:]
    // ---- final projection + LN + gelu ----
    gemm(fused, 1536, wp, BROWS, 768, 1536, fp_b,
         nullptr, 0, nullptr, 0, nullptr, 0, pbuf, 768, 0);
    ln_k<<<dim3(BROWS), dim3(256), 0, stream>>>(
        pbuf, nullptr, fp_ln_g, fp_ln_b, (float*)d_out, nullptr, 1);
}

// Round 7
// 1031.514 us; speedup vs baseline: 1.1640x; 1.0453x over previous
//
#include <hip/hip_runtime.h>
#include <hip/hip_bf16.h>
#include <math.h>

// CrossAttentionFusion on MI355X.
// softmax over one key == 1  =>  mha1(q_in, kv) = kv@Wc.T + bc,
//   Wc = Wo@Wv (fused once), bc = Wo@bv + bo.
// R12: attribution round. The dispatch-sum model (1550 cy/phase) accounts for
// only ~695us of the measured 1078us; top-5 only ever shows the FFN2 class.
// gemm_bt is now template<int TAG> (0=attn,1=ffn1,2=ffn2,3=fp) so rocprof
// names distinguish call-sites. Loop body EXACTLY R11 (verified). ln_k
// rewritten wave-per-row (no LDS, no barriers, all 64 lanes active).

typedef unsigned short u16;
typedef __bf16 bf16_t;
typedef bf16_t bf16x8 __attribute__((ext_vector_type(8)));
typedef float f32x4 __attribute__((ext_vector_type(4)));

#define BROWS 16384   // batch
#define EDIM  768

__device__ __forceinline__ u16 f2bf(float f) {
    union { float f; unsigned u; } v; v.f = f;
    return (u16)((v.u + 0x7FFFu + ((v.u >> 16) & 1u)) >> 16);  // RNE
}
__device__ __forceinline__ float bf2f(u16 h) {
    union { unsigned u; float f; } v; v.u = ((unsigned)h) << 16;
    return v.f;
}
// gelu via x*sigmoid(1.5957691*x + 0.0713548*x^3); exp2/rcp HW instrs.
__device__ __forceinline__ float gelu_f(float x) {
    float t = x * x;
    float p = fmaf(0.102943268f, t, 2.30221895f);   // log2(e) folded in
    float e = __builtin_amdgcn_exp2f(-x * p);
    return x * __builtin_amdgcn_rcpf(1.0f + e);
}

// async global->LDS, 16B/lane. LDS dest is wave-uniform base + lane*16.
__device__ __forceinline__ void gld16(const u16* g, u16* l) {
    __builtin_amdgcn_global_load_lds(
        (__attribute__((address_space(1))) void*)g,
        (__attribute__((address_space(3))) void*)l, 16, 0, 0);
}

// ---- batched f32->bf16 conversion: 8 tensors, one dispatch ----
struct ConvBatch {
    const float *s0, *s1, *s2, *s3, *s4, *s5, *s6, *s7;
    u16 *d0, *d1, *d2, *d3, *d4, *d5, *d6, *d7;
};
#define CB0 2304   // fi_W1 3072*768
#define CB1 2304   // fi_W2
#define CB2 2304   // ft_W1
#define CB3 2304   // ft_W2
#define CB4 1152   // fp_W 768*1536
#define CB5 576    // it_Wo 768*768
#define CB6 576    // ti_Wo
#define CB7 12288  // text 16384*768
#define CONV_BLOCKS (CB0+CB1+CB2+CB3+CB4+CB5+CB6+CB7)

__global__ void __launch_bounds__(256) conv8_k(ConvBatch cb) {
    int b = blockIdx.x;
    const float* s; u16* d;
    if      (b < CB0)          { s = cb.s0; d = cb.d0; }
    else if ((b -= CB0) < CB1) { s = cb.s1; d = cb.d1; }
    else if ((b -= CB1) < CB2) { s = cb.s2; d = cb.d2; }
    else if ((b -= CB2) < CB3) { s = cb.s3; d = cb.d3; }
    else if ((b -= CB3) < CB4) { s = cb.s4; d = cb.d4; }
    else if ((b -= CB4) < CB5) { s = cb.s5; d = cb.d5; }
    else if ((b -= CB5) < CB6) { s = cb.s6; d = cb.d6; }
    else    { b -= CB6;          s = cb.s7; d = cb.d7; }
    int i = b * 256 + threadIdx.x;
    float4 v = ((const float4*)s)[i];
    ushort4 o;
    o.x = f2bf(v.x); o.y = f2bf(v.y); o.z = f2bf(v.z); o.w = f2bf(v.w);
    ((ushort4*)d)[i] = o;
}

// D[c,r] = bf16(S[r,c]) — transpose-convert (Wv.T for the weight combine).
__global__ void __launch_bounds__(256) f32_to_bf16_T_k(const float* __restrict__ S,
                                                       u16* __restrict__ D,
                                                       int R, int C) {
    __shared__ float t[32][33];
    const int r0 = blockIdx.y * 32, c0 = blockIdx.x * 32;
    const int tx = threadIdx.x & 31, ty = threadIdx.x >> 5;  // ty 0..7
#pragma unroll
    for (int i = ty; i < 32; i += 8) t[i][tx] = S[(long)(r0 + i) * C + c0 + tx];
    __syncthreads();
#pragma unroll
    for (int i = ty; i < 32; i += 8) D[(long)(c0 + i) * R + r0 + tx] = f2bf(t[tx][i]);
}

// bc[n] = bo[n] + dot(Wo[n,:], bv)
__global__ void __launch_bounds__(256) bias_comb_k(const float* __restrict__ Wo,
                                                   const float* __restrict__ bv,
                                                   const float* __restrict__ bo,
                                                   float* __restrict__ bc, int K) {
    const int n = blockIdx.x * 4 + (threadIdx.x >> 6);
    const int lane = threadIdx.x & 63;
    float s = 0.f;
    for (int k = lane; k < K; k += 64) s += Wo[(long)n * K + k] * bv[k];
#pragma unroll
    for (int o = 32; o > 0; o >>= 1) s += __shfl_down(s, o, 64);
    if (lane == 0) bc[n] = s + bo[n];
}

// ---- small GEMM (128x128 tile, BK=32, 2-phase, 4 waves) for the 768^3
// weight combines. R5-verified structure; harness-verified in R10/R11.
__global__ void __launch_bounds__(256) gemm128_k(
    const u16* __restrict__ A, int lda,
    const u16* __restrict__ W,
    u16* __restrict__ Cb, int ldcb, int K)
{
    __shared__ alignas(16) u16 sA[2][128 * 32];
    __shared__ alignas(16) u16 sB[2][128 * 32];
    const int tid  = threadIdx.x;
    const int lane = tid & 63;
    const int wave = tid >> 6;
    const int wm = wave >> 1, wn = wave & 1;
    const long m0 = (long)blockIdx.y * 128;
    const long n0 = (long)blockIdx.x * 128;
    const int r   = lane >> 2;
    const int cbk = lane & 3;
    const int cbs = cbk ^ ((r >> 1) & 3);
    const int c0 = wave * 2, c1 = wave * 2 + 1;
    const u16* gA0 = A + (m0 + c0 * 16 + r) * (long)lda + cbs * 8;
    const u16* gA1 = A + (m0 + c1 * 16 + r) * (long)lda + cbs * 8;
    const u16* gB0 = W + (n0 + c0 * 16 + r) * (long)K + cbs * 8;
    const u16* gB1 = W + (n0 + c1 * 16 + r) * (long)K + cbs * 8;
    auto stage = [&](int buf, int kk) {
        gld16(gA0 + kk, sA[buf] + c0 * 512);
        gld16(gA1 + kk, sA[buf] + c1 * 512);
        gld16(gB0 + kk, sB[buf] + c0 * 512);
        gld16(gB1 + kk, sB[buf] + c1 * 512);
    };
    const int quad = lane >> 4;
    const int l16  = lane & 15;
    int offA[4], offB[4];
#pragma unroll
    for (int t = 0; t < 4; t++) {
        const int rowA = wm * 64 + t * 16 + l16;
        const int rowB = wn * 64 + t * 16 + l16;
        offA[t] = rowA * 32 + (quad ^ ((rowA >> 1) & 3)) * 8;
        offB[t] = rowB * 32 + (quad ^ ((rowB >> 1) & 3)) * 8;
    }
    f32x4 acc[4][4];
#pragma unroll
    for (int i = 0; i < 4; i++)
#pragma unroll
        for (int j = 0; j < 4; j++) {
            f32x4 z = {0.f, 0.f, 0.f, 0.f};
            acc[i][j] = z;
        }
    stage(0, 0);
    __syncthreads();
    int buf = 0;
    for (int k0 = 0; k0 < K; k0 += 32) {
        const int nk = k0 + 32;
        if (nk < K) stage(buf ^ 1, nk);
        bf16x8 af[4], bfr[4];
#pragma unroll
        for (int t = 0; t < 4; t++) af[t]  = *(const bf16x8*)(sA[buf] + offA[t]);
#pragma unroll
        for (int t = 0; t < 4; t++) bfr[t] = *(const bf16x8*)(sB[buf] + offB[t]);
#pragma unroll
        for (int mt = 0; mt < 4; mt++)
#pragma unroll
            for (int nt = 0; nt < 4; nt++)
                acc[mt][nt] = __builtin_amdgcn_mfma_f32_16x16x32_bf16(
                    af[mt], bfr[nt], acc[mt][nt], 0, 0, 0);
        __syncthreads();
        buf ^= 1;
    }
#pragma unroll
    for (int mt = 0; mt < 4; mt++)
#pragma unroll
        for (int nt = 0; nt < 4; nt++) {
            const long col = n0 + wn * 64 + nt * 16 + l16;
#pragma unroll
            for (int rr = 0; rr < 4; rr++) {
                const long row = m0 + wm * 64 + mt * 16 + quad * 4 + rr;
                Cb[row * (long)ldcb + col] = f2bf(acc[mt][nt][rr]);
            }
        }
}

// C[m,n] = sum_k A[m,k] * W[n,k]  (+bias, +f32 or bf16 residual, opt gelu)
// 256x256 tile, 8 waves (2M x 4N), per-wave C = 128x64. One barrier/phase,
// fragment reads pipelined one phase ahead (counted lgkmcnt). (R9/R11 loop,
// body unchanged.) TAG only distinguishes call-sites in rocprof:
// 0=attn, 1=ffn1, 2=ffn2, 3=fp.
template <int TAG>
__global__ void __launch_bounds__(512, 2) gemm_bt(
    const u16* __restrict__ A, int lda,
    const u16* __restrict__ W,
    const float* __restrict__ bias,
    const float* __restrict__ R, int ldr,      // f32 residual (or null)
    const u16* __restrict__ Rb, int ldrb,      // bf16 residual (or null)
    float* __restrict__ Cf, int ldcf,
    u16* __restrict__ Cb, int ldcb,
    int K, int do_gelu)
{
    __shared__ alignas(16) u16 sA[4][256 * 32];   // 4 k-half slots x 16KB
    __shared__ alignas(16) u16 sB[4][256 * 32];

    const int tid  = threadIdx.x;
    const int lane = tid & 63;
    const int wave = tid >> 6;     // 0..7
    const int wm = wave >> 2;      // 0..1  (M half)
    const int wn = wave & 3;       // 0..3  (N quarter)

    // XCD-aware swizzle: id%8 = XCD (round-robin dispatch). Give each XCD a
    // contiguous slab of row-tiles; sweep col-tiles fastest within the slab.
    int bm, bn;
    {
        const int gx = gridDim.x, gy = gridDim.y;
        const int id = blockIdx.y * gx + blockIdx.x;
        if ((gy & 7) == 0) {
            const int xcd = id & 7, slot = id >> 3;
            bn = slot % gx;
            bm = (xcd * (gy >> 3)) + slot / gx;
        } else { bm = blockIdx.y; bn = blockIdx.x; }
    }
    const long m0 = (long)bm * 256;
    const long n0 = (long)bn * 256;

    // Staging: one 16KB half per phase = 2 gld16/thread.
    // Lane l of wave w covers LDS row (rd*128 + w*16 + (l>>2)), 16B-block
    // (l&3); LDS offset = rd*8192 + w*1024 + l*16 (linear per wave, DMA-ok).
    // Bank swizzle: LDS block b of row r holds global k-block b^((r>>1)&3)
    // -> source k-block = (l&3) ^ ((l>>3)&3). Reads un-XOR it.
    const int srow = lane >> 2;                          // 0..15
    const int sk   = ((lane & 3) ^ ((lane >> 3) & 3)) * 8;
    const u16* gA = A + (m0 + wave * 16 + srow) * (long)lda + sk;
    const u16* gB = W + (n0 + wave * 16 + srow) * (long)K + sk;
    const long rdA2 = 128 * (long)lda;
    const long rdB2 = 128 * (long)K;

#define STA(sl, t, ks) do { const u16* g_ = gA + (t) * 64 + (ks) * 32; \
    gld16(g_,        &sA[sl][wave * 512]); \
    gld16(g_ + rdA2, &sA[sl][4096 + wave * 512]); } while (0)
#define STB(sl, t, ks) do { const u16* g_ = gB + (t) * 64 + (ks) * 32; \
    gld16(g_,        &sB[sl][wave * 512]); \
    gld16(g_ + rdB2, &sB[sl][4096 + wave * 512]); } while (0)

    const int quad = lane >> 4;    // 0..3 -> k = quad*8 + j
    const int l16  = lane & 15;    // m (A) / n (B) index within fragment
    const int koff = (quad ^ ((l16 >> 1) & 3)) << 4;     // un-swizzled 16B blk
    __attribute__((address_space(3))) const u16* baseA3 =
        (__attribute__((address_space(3))) const u16*)
        ((const char*)&sA[0][0] + wm * 8192 + l16 * 64 + koff);
    __attribute__((address_space(3))) const u16* baseB3 =
        (__attribute__((address_space(3))) const u16*)
        ((const char*)&sB[0][0] + wn * 4096 + l16 * 64 + koff);

    f32x4 acc[8][4];
#pragma unroll
    for (int i = 0; i < 8; i++)
#pragma unroll
        for (int j = 0; j < 4; j++) {
            f32x4 z = {0.f, 0.f, 0.f, 0.f};
            acc[i][j] = z;
        }
    // double-buffered fragment sets (static names; no runtime indexing)
    bf16x8 a0_0, a0_1, a0_2, a0_3;   // A set 0
    bf16x8 a1_0, a1_1, a1_2, a1_3;   // A set 1
    bf16x8 b0_0, b0_1, b0_2, b0_3;   // B set 0
    bf16x8 b1_0, b1_1, b1_2, b1_3;   // B set 1

// asm ds_read: invisible to the backend's waitcnt pass; completion governed
// solely by our counted lgkmcnt (rule 18: fence with sched_barrier).
#define DSR(dst, base, off) \
    asm volatile("ds_read_b128 %0, %1 offset:%2" \
                 : "=v"(dst) : "v"(base), "i"(off))
#define RDA(S, SLA, MQ) do { \
    DSR(a##S##_0, baseA3, (SLA) * 16384 + (MQ) * 4096 + 0);    \
    DSR(a##S##_1, baseA3, (SLA) * 16384 + (MQ) * 4096 + 1024); \
    DSR(a##S##_2, baseA3, (SLA) * 16384 + (MQ) * 4096 + 2048); \
    DSR(a##S##_3, baseA3, (SLA) * 16384 + (MQ) * 4096 + 3072); \
  } while (0)
#define RDB(S, SLB) do { \
    DSR(b##S##_0, baseB3, (SLB) * 16384 + 0);    \
    DSR(b##S##_1, baseB3, (SLB) * 16384 + 1024); \
    DSR(b##S##_2, baseB3, (SLB) * 16384 + 2048); \
    DSR(b##S##_3, baseB3, (SLB) * 16384 + 3072); \
  } while (0)

#define MM16(AS, BS, MQ) do { \
    acc[(MQ)*4+0][0] = __builtin_amdgcn_mfma_f32_16x16x32_bf16(a##AS##_0, b##BS##_0, acc[(MQ)*4+0][0], 0, 0, 0); \
    acc[(MQ)*4+0][1] = __builtin_amdgcn_mfma_f32_16x16x32_bf16(a##AS##_0, b##BS##_1, acc[(MQ)*4+0][1], 0, 0, 0); \
    acc[(MQ)*4+0][2] = __builtin_amdgcn_mfma_f32_16x16x32_bf16(a##AS##_0, b##BS##_2, acc[(MQ)*4+0][2], 0, 0, 0); \
    acc[(MQ)*4+0][3] = __builtin_amdgcn_mfma_f32_16x16x32_bf16(a##AS##_0, b##BS##_3, acc[(MQ)*4+0][3], 0, 0, 0); \
    acc[(MQ)*4+1][0] = __builtin_amdgcn_mfma_f32_16x16x32_bf16(a##AS##_1, b##BS##_0, acc[(MQ)*4+1][0], 0, 0, 0); \
    acc[(MQ)*4+1][1] = __builtin_amdgcn_mfma_f32_16x16x32_bf16(a##AS##_1, b##BS##_1, acc[(MQ)*4+1][1], 0, 0, 0); \
    acc[(MQ)*4+1][2] = __builtin_amdgcn_mfma_f32_16x16x32_bf16(a##AS##_1, b##BS##_2, acc[(MQ)*4+1][2], 0, 0, 0); \
    acc[(MQ)*4+1][3] = __builtin_amdgcn_mfma_f32_16x16x32_bf16(a##AS##_1, b##BS##_3, acc[(MQ)*4+1][3], 0, 0, 0); \
    acc[(MQ)*4+2][0] = __builtin_amdgcn_mfma_f32_16x16x32_bf16(a##AS##_2, b##BS##_0, acc[(MQ)*4+2][0], 0, 0, 0); \
    acc[(MQ)*4+2][1] = __builtin_amdgcn_mfma_f32_16x16x32_bf16(a##AS##_2, b##BS##_1, acc[(MQ)*4+2][1], 0, 0, 0); \
    acc[(MQ)*4+2][2] = __builtin_amdgcn_mfma_f32_16x16x32_bf16(a##AS##_2, b##BS##_2, acc[(MQ)*4+2][2], 0, 0, 0); \
    acc[(MQ)*4+2][3] = __builtin_amdgcn_mfma_f32_16x16x32_bf16(a##AS##_2, b##BS##_3, acc[(MQ)*4+2][3], 0, 0, 0); \
    acc[(MQ)*4+3][0] = __builtin_amdgcn_mfma_f32_16x16x32_bf16(a##AS##_3, b##BS##_0, acc[(MQ)*4+3][0], 0, 0, 0); \
    acc[(MQ)*4+3][1] = __builtin_amdgcn_mfma_f32_16x16x32_bf16(a##AS##_3, b##BS##_1, acc[(MQ)*4+3][1], 0, 0, 0); \
    acc[(MQ)*4+3][2] = __builtin_amdgcn_mfma_f32_16x16x32_bf16(a##AS##_3, b##BS##_2, acc[(MQ)*4+3][2], 0, 0, 0); \
    acc[(MQ)*4+3][3] = __builtin_amdgcn_mfma_f32_16x16x32_bf16(a##AS##_3, b##BS##_3, acc[(MQ)*4+3][3], 0, 0, 0); \
  } while (0)

// phase top: optional slot-verify vmcnt, the ONE barrier, pin reads after it.
#define PH_TOP0 do { \
    __builtin_amdgcn_s_barrier(); \
    __builtin_amdgcn_sched_barrier(0); } while (0)
#define PH_TOP1 do { \
    asm volatile("s_waitcnt vmcnt(6)" ::: "memory"); \
    __builtin_amdgcn_s_barrier(); \
    __builtin_amdgcn_sched_barrier(0); } while (0)
// phase bottom: counted lgkm (this phase's frags done, next phase's in
// flight), fence (rule 18), MFMA cluster under setprio.
#define PH_BOT(LGK, AS, BS, MQ) do { \
    asm volatile("s_waitcnt lgkmcnt(%0)" :: "i"(LGK) : "memory"); \
    __builtin_amdgcn_sched_barrier(0); \
    __builtin_amdgcn_s_setprio(1); \
    MM16(AS, BS, MQ); \
    __builtin_amdgcn_s_setprio(0); } while (0)

    const int nt = K >> 6;     // 64-wide K-tiles; nt even, >= 4 (K >= 256)
    // Prologue: stage slots A0,B0,A1,B1,A2,B2 (12 loads); land A0,B0;
    // issue phase-1 fragments (A slot0 mq0 + B slot0).
    STA(0, 0, 0); STB(0, 0, 0);
    STA(1, 0, 1); STB(1, 0, 1);
    STA(2, 1, 0); STB(2, 1, 0);
    asm volatile("s_waitcnt vmcnt(8)" ::: "memory");
    __builtin_amdgcn_s_barrier();
    __builtin_amdgcn_sched_barrier(0);
    RDA(0, 0, 0); RDB(0, 0);

    for (int T = 0; T < nt; T += 2) {
        const int t2 = (T + 2 < nt) ? T + 2 : 0;   // tail: wrap-stage (reads
        const int t3 = (T + 3 < nt) ? T + 3 : 1;   // of wrap land in dead regs)
        // Ph1 (T,0,0)
        PH_TOP0; RDA(1, 0, 1);            STA(3, T + 1, 1); PH_BOT(4, 0, 0, 0);
        // Ph2 (T,0,1)
        PH_TOP1; RDA(0, 1, 0); RDB(1, 1); STB(3, T + 1, 1); PH_BOT(8, 1, 0, 1);
        // Ph3 (T,1,0)
        PH_TOP0; RDA(1, 1, 1);            STA(0, t2, 0);    PH_BOT(4, 0, 1, 0);
        // Ph4 (T,1,1)
        PH_TOP1; RDA(0, 2, 0); RDB(0, 2); STB(0, t2, 0);    PH_BOT(8, 1, 1, 1);
        // Ph5 (T+1,0,0)
        PH_TOP0; RDA(1, 2, 1);            STA(1, t2, 1);    PH_BOT(4, 0, 0, 0);
        // Ph6 (T+1,0,1)
        PH_TOP1; RDA(0, 3, 0); RDB(1, 3); STB(1, t2, 1);    PH_BOT(8, 1, 0, 1);
        // Ph7 (T+1,1,0)
        PH_TOP0; RDA(1, 3, 1);            STA(2, t3, 0);    PH_BOT(4, 0, 1, 0);
        // Ph8 (T+1,1,1)
        PH_TOP1; RDA(0, 0, 0); RDB(0, 0); STB(2, t3, 0);    PH_BOT(8, 1, 1, 1);
    }
    // drain: late LDS returns must not clobber reallocated VGPRs.
    asm volatile("s_waitcnt lgkmcnt(0)" ::: "memory");
    __builtin_amdgcn_sched_barrier(0);

    // epilogue: C/D layout col = lane&15, row = quad*4 + reg  [m89/m91]
#pragma unroll
    for (int mt = 0; mt < 8; mt++) {
#pragma unroll
        for (int nf = 0; nf < 4; nf++) {
            const long col = n0 + wn * 64 + nf * 16 + l16;
            const float bv = bias ? bias[col] : 0.0f;
#pragma unroll
            for (int rr = 0; rr < 4; rr++) {
                const long row = m0 + wm * 128 + mt * 16 + quad * 4 + rr;
                float v = acc[mt][nf][rr] + bv;
                if (R)  v += R[row * (long)ldr + col];
                if (Rb) v += bf2f(Rb[row * (long)ldrb + col]);
                if (do_gelu) v = gelu_f(v);
                if (Cf) Cf[row * (long)ldcf + col] = v;
                if (Cb) Cb[row * (long)ldcb + col] = f2bf(v);
            }
        }
    }
#undef PH_TOP0
#undef PH_TOP1
#undef PH_BOT
#undef MM16
#undef RDA
#undef RDB
#undef DSR
#undef STA
#undef STB
}

// LayerNorm over 768 cols. R12: one WAVE per row (4 rows per 256-thr block),
// full shfl_xor butterfly -> all lanes hold the sums; no LDS, no barriers,
// all 64 lanes active (12 elems/lane). Input bf16 (Xb) or f32 (Xf);
// output f32 (Yf) and/or bf16 (Yb); optional gelu.
__global__ void __launch_bounds__(256) ln_k(
    const u16*  __restrict__ Xb,
    const float* __restrict__ Xf,
    const float* __restrict__ g,
    const float* __restrict__ b,
    float* __restrict__ Yf,
    u16*   __restrict__ Yb,
    int do_gelu)
{
    const int row  = blockIdx.x * 4 + (threadIdx.x >> 6);
    const int lane = threadIdx.x & 63;
    float v[12];
    if (Xb) {
        const u16* xr = Xb + (long)row * EDIM;
#pragma unroll
        for (int j = 0; j < 3; j++) {
            ushort4 u = ((const ushort4*)xr)[lane + j * 64];
            v[j*4+0] = bf2f(u.x); v[j*4+1] = bf2f(u.y);
            v[j*4+2] = bf2f(u.z); v[j*4+3] = bf2f(u.w);
        }
    } else {
        const float* xr = Xf + (long)row * EDIM;
#pragma unroll
        for (int j = 0; j < 3; j++) {
            float4 f = ((const float4*)xr)[lane + j * 64];
            v[j*4+0] = f.x; v[j*4+1] = f.y; v[j*4+2] = f.z; v[j*4+3] = f.w;
        }
    }
    float s = 0.f, s2 = 0.f;
#pragma unroll
    for (int j = 0; j < 12; j++) { s += v[j]; s2 += v[j] * v[j]; }
#pragma unroll
    for (int o = 32; o > 0; o >>= 1) {
        s  += __shfl_xor(s,  o, 64);
        s2 += __shfl_xor(s2, o, 64);
    }
    const float mean = s * (1.0f / 768.0f);
    const float inv  = rsqrtf(s2 * (1.0f / 768.0f) - mean * mean + 1e-5f);
#pragma unroll
    for (int j = 0; j < 3; j++) {
        float4 gv = ((const float4*)g)[lane + j * 64];
        float4 bvv = ((const float4*)b)[lane + j * 64];
        float y0 = (v[j*4+0] - mean) * inv * gv.x + bvv.x;
        float y1 = (v[j*4+1] - mean) * inv * gv.y + bvv.y;
        float y2 = (v[j*4+2] - mean) * inv * gv.z + bvv.z;
        float y3 = (v[j*4+3] - mean) * inv * gv.w + bvv.w;
        if (do_gelu) {
            y0 = gelu_f(y0); y1 = gelu_f(y1); y2 = gelu_f(y2); y3 = gelu_f(y3);
        }
        if (Yf) {
            float4 o = {y0, y1, y2, y3};
            ((float4*)(Yf + (long)row * EDIM))[lane + j * 64] = o;
        }
        if (Yb) {
            ushort4 o = {f2bf(y0), f2bf(y1), f2bf(y2), f2bf(y3)};
            ((ushort4*)(Yb + (long)row * EDIM))[lane + j * 64] = o;
        }
    }
}

extern "C" void kernel_launch(void* const* d_in, const int* in_sizes, int n_in,
                              void* d_out, int out_size, void* d_ws, size_t ws_size,
                              hipStream_t stream) {
    (void)in_sizes; (void)n_in; (void)out_size;
    const float* image    = (const float*)d_in[0];
    const float* text     = (const float*)d_in[1];
    const float* it_Wv    = (const float*)d_in[4];
    const float* it_Wo    = (const float*)d_in[5];
    const float* it_bv    = (const float*)d_in[8];
    const float* it_bo    = (const float*)d_in[9];
    const float* ti_Wv    = (const float*)d_in[12];
    const float* ti_Wo    = (const float*)d_in[13];
    const float* ti_bv    = (const float*)d_in[16];
    const float* ti_bo    = (const float*)d_in[17];
    const float* ln_img_g = (const float*)d_in[18];
    const float* ln_img_b = (const float*)d_in[19];
    const float* ln_txt_g = (const float*)d_in[20];
    const float* ln_txt_b = (const float*)d_in[21];
    const float* fp_ln_g  = (const float*)d_in[22];
    const float* fp_ln_b  = (const float*)d_in[23];
    const float* fi_W1    = (const float*)d_in[24];
    const float* fi_b1    = (const float*)d_in[25];
    const float* fi_W2    = (const float*)d_in[26];
    const float* fi_b2    = (const float*)d_in[27];
    const float* ft_W1    = (const float*)d_in[28];
    const float* ft_b1    = (const float*)d_in[29];
    const float* ft_W2    = (const float*)d_in[30];
    const float* ft_b2    = (const float*)d_in[31];
    const float* fp_W     = (const float*)d_in[32];
    const float* fp_b     = (const float*)d_in[33];

    char* ws = (char*)d_ws;
    size_t off = 0;
    auto alloc = [&](size_t bytes) {
        char* p = ws + off; off += (bytes + 255) & ~(size_t)255; return p;
    };
    // bf16 weights (~28 MB, live whole call)
    u16* wo_it = (u16*)alloc((size_t)768 * 768 * 2);
    u16* wvT_it= (u16*)alloc((size_t)768 * 768 * 2);
    u16* wc_it = (u16*)alloc((size_t)768 * 768 * 2);
    u16* wo_ti = (u16*)alloc((size_t)768 * 768 * 2);
    u16* wvT_ti= (u16*)alloc((size_t)768 * 768 * 2);
    u16* wc_ti = (u16*)alloc((size_t)768 * 768 * 2);
    u16* w1i   = (u16*)alloc((size_t)3072 * 768 * 2);
    u16* w2i   = (u16*)alloc((size_t)768 * 3072 * 2);
    u16* w1t   = (u16*)alloc((size_t)3072 * 768 * 2);
    u16* w2t   = (u16*)alloc((size_t)768 * 3072 * 2);
    u16* wp    = (u16*)alloc((size_t)768 * 1536 * 2);
    float* bc_it = (float*)alloc(768 * 4);
    float* bc_ti = (float*)alloc(768 * 4);
    // activations
    u16* vbuf  = (u16*)alloc((size_t)BROWS * 768 * 2);   // post-LN bf16
    u16* fused = (u16*)alloc((size_t)BROWS * 1536 * 2);  // [img | txt] bf16
    u16* text_bf = fused;     // alias: text_bf dead before fused is written
    // hbuf (FFN hidden, adaptive chunk) and pbuf (bf16 pre-LN) share a region.
    int fch = 16384;
    while (fch > 2048 && off + (size_t)fch * 3072 * 2 > ws_size) fch >>= 1;
    size_t region = (size_t)fch * 3072 * 2;
    if (region < (size_t)BROWS * 768 * 2) region = (size_t)BROWS * 768 * 2;
    u16* hbuf = (u16*)alloc(region);
    u16* pbuf = hbuf;

    auto gemm = [&](int tag, const u16* A, int lda, const u16* W, int M, int N,
                    int K, const float* bias, const float* R, int ldr,
                    const u16* Rb, int ldrb,
                    float* Cf, int ldcf, u16* Cb, int ldcb, int dg) {
        dim3 gr(N / 256, M / 256), bl(512);
        if (tag == 0)
            gemm_bt<0><<<gr, bl, 0, stream>>>(A, lda, W, bias, R, ldr, Rb, ldrb,
                                              Cf, ldcf, Cb, ldcb, K, dg);
        else if (tag == 1)
            gemm_bt<1><<<gr, bl, 0, stream>>>(A, lda, W, bias, R, ldr, Rb, ldrb,
                                              Cf, ldcf, Cb, ldcb, K, dg);
        else if (tag == 2)
            gemm_bt<2><<<gr, bl, 0, stream>>>(A, lda, W, bias, R, ldr, Rb, ldrb,
                                              Cf, ldcf, Cb, ldcb, K, dg);
        else
            gemm_bt<3><<<gr, bl, 0, stream>>>(A, lda, W, bias, R, ldr, Rb, ldrb,
                                              Cf, ldcf, Cb, ldcb, K, dg);
    };
    auto ffn = [&](const u16* xin, const u16* W1, const float* b1,
                   const u16* W2, const float* b2, u16* outp, int ldout) {
        for (int c = 0; c < BROWS / fch; c++) {
            const u16* xc = xin + (size_t)c * fch * 768;
            gemm(1, xc, 768, W1, fch, 3072, 768, b1,
                 nullptr, 0, nullptr, 0, nullptr, 0, hbuf, 3072, 1);
            gemm(2, hbuf, 3072, W2, fch, 768, 3072, b2,
                 nullptr, 0, xc, 768,
                 nullptr, 0, outp + (size_t)c * fch * ldout, ldout, 0);
        }
    };

    // ---- conversions: one batched dispatch ----
    ConvBatch cbt = { fi_W1, fi_W2, ft_W1, ft_W2, fp_W, it_Wo, ti_Wo, text,
                      w1i,   w2i,   w1t,   w2t,   wp,   wo_it, wo_ti, text_bf };
    conv8_k<<<dim3(CONV_BLOCKS), dim3(256), 0, stream>>>(cbt);
    // ---- weight combine: Wc = Wo@Wv (bf16), bc = Wo@bv + bo ----
    f32_to_bf16_T_k<<<dim3(24, 24), dim3(256), 0, stream>>>(it_Wv, wvT_it, 768, 768);
    f32_to_bf16_T_k<<<dim3(24, 24), dim3(256), 0, stream>>>(ti_Wv, wvT_ti, 768, 768);
    gemm128_k<<<dim3(6, 6), dim3(256), 0, stream>>>(wo_it, 768, wvT_it, wc_it, 768, 768);
    gemm128_k<<<dim3(6, 6), dim3(256), 0, stream>>>(wo_ti, 768, wvT_ti, wc_ti, 768, 768);
    bias_comb_k<<<dim3(192), dim3(256), 0, stream>>>(it_Wo, it_bv, it_bo, bc_it, 768);
    bias_comb_k<<<dim3(192), dim3(256), 0, stream>>>(ti_Wo, ti_bv, ti_bo, bc_ti, 768);

    // ---- image path: att = text@Wc.T + bc + image ; LN1 ----
    gemm(0, text_bf, 768, wc_it, BROWS, 768, 768, bc_it,
         image, 768, nullptr, 0, nullptr, 0, pbuf, 768, 0);
    ln_k<<<dim3(BROWS / 4), dim3(256), 0, stream>>>(
        pbuf, nullptr, ln_img_g, ln_img_b, nullptr, vbuf, 0);
    ffn(vbuf, w1i, fi_b1, w2i, fi_b2, fused, 1536);   // -> fused[:, :768]
    // ---- text path: kv = post-FFN img (fused left half) ----
    gemm(0, fused, 1536, wc_ti, BROWS, 768, 768, bc_ti,
         text, 768, nullptr, 0, nullptr, 0, pbuf, 768, 0);
    ln_k<<<dim3(BROWS / 4), dim3(256), 0, stream>>>(
        pbuf, nullptr, ln_txt_g, ln_txt_b, nullptr, vbuf, 0);
    ffn(vbuf, w1t, ft_b1, w2t, ft_b2, fused + 768, 1536);  // -> fused[:, 768:]
    // ---- final projection + LN + gelu ----
    gemm(3, fused, 1536, wp, BROWS, 768, 1536, fp_b,
         nullptr, 0, nullptr, 0, nullptr, 0, pbuf, 768, 0);
    ln_k<<<dim3(BROWS / 4), dim3(256), 0, stream>>>(
        pbuf, nullptr, fp_ln_g, fp_ln_b, (float*)d_out, nullptr, 1);
}